// Round 5
// baseline (17433.929 us; speedup 1.0000x reference)
//
#include <hip/hip_runtime.h>
#include <hip/hip_bf16.h>

typedef __hip_bfloat16 bf16;

#define B_ 512
#define T_ 150
#define S_ 151
#define D_ 256
#define H_ 8
#define HD_ 32
#define FF_ 1024
#define NC_ 4
#define DEPTH_ 6

// Chunked execution: RBC batches per chunk, full depth per chunk.
#define RBC 128
#define RROWS (RBC * S_)            // 19328 rows = 302 * 64 exactly
#define XOFF 0
#define C1OFF (RROWS * D_)          // x region: RROWS*256
#define C2OFF (C1OFF + RROWS * FF_) // c1 region: RROWS*1024 (qkv/ffn/y reuse)
#define WSELEMS (C2OFF + RROWS * D_)// c2 region: RROWS*256

// Static f32 workspace (~118.7 MB). Every element read in a call is written
// earlier in the SAME call. (d_ws proved unusable in rounds 1-3.)
__device__ __align__(16) float g_ws[WSELEMS];
// 1 => external buffers are float32; 0 => bf16. Set by probe_kernel each call.
__device__ int g_f32flag;

// Flexible external load: i indexes ELEMENTS of the true dtype.
__device__ __forceinline__ float ldf(const void* p, size_t i, int f) {
  return f ? ((const float*)p)[i] : __bfloat162float(((const bf16*)p)[i]);
}

// ---------------------------------------------------------------------------
// Dtype probe on pos_embed (38656 elems, ~N(0,0.02^2)), scanned as bf16 words.
// bf16 data: small values, no giant exponents, even words nonzero.
// f32 data: junk low-halves -> exponent>=141 hits; bf16-rounded-in-f32 ->
// even words all zero. Deterministic (same inputs every call).
// ---------------------------------------------------------------------------
#define PROBE_N 38656
__global__ __launch_bounds__(256) void probe_kernel(const void* pe)
{
  const unsigned short* w = (const unsigned short*)pe;
  int susp = 0, zeroEven = 0;
  for (int k = threadIdx.x; k < PROBE_N; k += 256) {
    unsigned short u = w[k];
    int ex = (u >> 7) & 0xFF;
    if (ex >= 141) susp++;                       // |v| >= 2^14 or NaN/Inf
    if ((k & 1) == 0 && (u & 0x7FFF) == 0) zeroEven++;
  }
  __shared__ int s_susp, s_zero;
  if (threadIdx.x == 0) { s_susp = 0; s_zero = 0; }
  __syncthreads();
  atomicAdd(&s_susp, susp);
  atomicAdd(&s_zero, zeroEven);
  __syncthreads();
  if (threadIdx.x == 0)
    g_f32flag = (s_susp > 0 || s_zero >= ((PROBE_N / 2) * 9) / 10) ? 1 : 0;
}

// ---------------------------------------------------------------------------
// Embedding for one chunk: global row = row0 + blockIdx.x -> chunk-local x.
// ---------------------------------------------------------------------------
__global__ __launch_bounds__(256) void embed_kernel(
    const int* __restrict__ tt, const int* __restrict__ dids,
    const void* av, const void* dv, const void* vv,
    const void* aW, const void* ab, const void* dW, const void* db,
    const void* vW, const void* vb, const void* table, const void* pos,
    const void* cls, int row0)
{
  const int f = g_f32flag;
  float* x = g_ws + XOFF;
  int row = row0 + blockIdx.x;
  int d = threadIdx.x;
  int b = row / S_;
  int s = row - b * S_;
  float val;
  if (s == 0) {
    val = ldf(cls, d, f);
  } else {
    int t = s - 1;
    int idx = b * T_ + t;
    int ty = tt[idx];
    if (ty == 0) {
      val = ldf(av, idx, f) * ldf(aW, d, f) + ldf(ab, d, f);
    } else if (ty == 1) {
      float acc = ldf(db, d, f) + ldf(vb, d, f);
#pragma unroll
      for (int i = 0; i < 10; i++) acc += ldf(dv, (size_t)idx * 10 + i, f) * ldf(dW, i * D_ + d, f);
#pragma unroll
      for (int i = 0; i < 3; i++) acc += ldf(vv, (size_t)idx * 3 + i, f) * ldf(vW, i * D_ + d, f);
      val = acc;
    } else if (ty == 2) {
      int did = dids[idx] & (NC_ - 1);
      val = ldf(table, (size_t)did * D_ + d, f);
    } else {
      val = 0.f;
    }
  }
  val += ldf(pos, s * D_ + d, f);
  x[(size_t)blockIdx.x * D_ + d] = val;
}

// ---------------------------------------------------------------------------
// Tiled GEMM on f32 workspace: C = A @ W + bias (optional relu).
// W/bias external with ELEMENT offsets wOff/bOff (dtype-independent).
// 64x64 tile, BK=16, 256 threads, 4x4/thread.
// ---------------------------------------------------------------------------
__global__ __launch_bounds__(256) void gemm_ws(
    int aOff, const void* W, size_t wOff, const void* bias, size_t bOff,
    int cOff, int M, int N, int K, int relu)
{
  const int f = g_f32flag;
  const float* A = g_ws + aOff;
  float* C = g_ws + cOff;
  __shared__ __align__(16) float As[16][68];  // [k][m]
  __shared__ __align__(16) float Bs[16][68];  // [k][n]
  const int tid = threadIdx.x;
  const int bm = blockIdx.y, bn = blockIdx.x;
  const int tx = tid & 15, ty = tid >> 4;
  const int ac = tid & 15, ar0 = tid >> 4;
  const int bc = tid & 63, br0 = tid >> 6;
  float acc[4][4] = {};
  for (int k0 = 0; k0 < K; k0 += 16) {
#pragma unroll
    for (int i = 0; i < 4; i++) {
      int ar = ar0 + i * 16;
      int grow = bm * 64 + ar;
      As[ac][ar] = (grow < M) ? A[(size_t)grow * K + k0 + ac] : 0.f;
    }
#pragma unroll
    for (int i = 0; i < 4; i++) {
      int br = br0 + i * 4;
      Bs[br][bc] = ldf(W, wOff + (size_t)(k0 + br) * N + bn * 64 + bc, f);
    }
    __syncthreads();
#pragma unroll
    for (int kk = 0; kk < 16; kk++) {
      float4 a4 = *(const float4*)&As[kk][ty * 4];
      float4 b4 = *(const float4*)&Bs[kk][tx * 4];
      float avv[4] = {a4.x, a4.y, a4.z, a4.w};
      float bvv[4] = {b4.x, b4.y, b4.z, b4.w};
#pragma unroll
      for (int i = 0; i < 4; i++)
#pragma unroll
        for (int j = 0; j < 4; j++)
          acc[i][j] += avv[i] * bvv[j];
    }
    __syncthreads();
  }
  float bfv[4];
#pragma unroll
  for (int j = 0; j < 4; j++) bfv[j] = ldf(bias, bOff + bn * 64 + tx * 4 + j, f);
#pragma unroll
  for (int i = 0; i < 4; i++) {
    int row = bm * 64 + ty * 4 + i;
    if (row < M) {
      float v0 = acc[i][0] + bfv[0], v1 = acc[i][1] + bfv[1];
      float v2 = acc[i][2] + bfv[2], v3 = acc[i][3] + bfv[3];
      if (relu) { v0 = fmaxf(v0, 0.f); v1 = fmaxf(v1, 0.f); v2 = fmaxf(v2, 0.f); v3 = fmaxf(v3, 0.f); }
      float4 outv; outv.x = v0; outv.y = v1; outv.z = v2; outv.w = v3;
      *(float4*)(C + (size_t)row * N + bn * 64 + tx * 4) = outv;
    }
  }
}

// ---------------------------------------------------------------------------
// Attention: one block per (b_local, h); qkv at g_ws+C1OFF (stride 768,
// [q|k|v]); output at g_ws+C2OFF (stride 256). Internal f32 throughout.
// ---------------------------------------------------------------------------
__global__ __launch_bounds__(192) void attn_kernel()
{
  const float* qkv = g_ws + C1OFF;
  float* o = g_ws + C2OFF;
  __shared__ float Ks[S_ * HD_];
  __shared__ float Vs[S_ * HD_];
  int bh = blockIdx.x;
  int b = bh >> 3, h = bh & 7;
  int tid = threadIdx.x;
  const float* base = qkv + (size_t)b * S_ * 768;
  for (int idx = tid; idx < S_ * HD_; idx += 192) {
    int j = idx >> 5, d = idx & 31;
    Ks[idx] = base[(size_t)j * 768 + 256 + h * 32 + d];
    Vs[idx] = base[(size_t)j * 768 + 512 + h * 32 + d];
  }
  __syncthreads();
  if (tid < S_) {
    const float scale = 0.17677669529663687f;  // 1/sqrt(32)
    float q[32];
    const float* qp = base + (size_t)tid * 768 + h * 32;
#pragma unroll
    for (int d = 0; d < 32; d++) q[d] = qp[d] * scale;
    float m = -1e30f, l = 0.f;
    float oa[32];
#pragma unroll
    for (int d = 0; d < 32; d++) oa[d] = 0.f;
    for (int j = 0; j < S_; j++) {
      const float* kp = &Ks[j * 32];
      float s = 0.f;
#pragma unroll
      for (int d = 0; d < 32; d++) s += q[d] * kp[d];
      float nm = fmaxf(m, s);
      float alpha = __expf(m - nm);
      float p = __expf(s - nm);
      l = l * alpha + p;
      const float* vp = &Vs[j * 32];
#pragma unroll
      for (int d = 0; d < 32; d++) oa[d] = oa[d] * alpha + p * vp[d];
      m = nm;
    }
    float inv = 1.f / l;
    float* op = o + (size_t)(b * S_ + tid) * D_ + h * 32;
#pragma unroll
    for (int d = 0; d < 32; d++) op[d] = oa[d] * inv;
  }
}

// ---------------------------------------------------------------------------
// x = LN(x + y) * g + b over D=256. gOff/bOff are element offsets.
// ---------------------------------------------------------------------------
__global__ __launch_bounds__(256) void resln_kernel(int yOff,
    const void* g, size_t gOff, const void* bta, size_t btaOff)
{
  const int f = g_f32flag;
  float* x = g_ws + XOFF;
  const float* y = g_ws + yOff;
  size_t row = blockIdx.x;
  int tid = threadIdx.x;
  float r = x[row * D_ + tid] + y[row * D_ + tid];
  float s1 = r, s2 = r * r;
#pragma unroll
  for (int off = 32; off > 0; off >>= 1) {
    s1 += __shfl_down(s1, off, 64);
    s2 += __shfl_down(s2, off, 64);
  }
  __shared__ float ws1[4], ws2[4], stats[2];
  int wid = tid >> 6, lane = tid & 63;
  if (lane == 0) { ws1[wid] = s1; ws2[wid] = s2; }
  __syncthreads();
  if (tid == 0) {
    float t1 = ws1[0] + ws1[1] + ws1[2] + ws1[3];
    float t2 = ws2[0] + ws2[1] + ws2[2] + ws2[3];
    float mean = t1 * (1.f / 256.f);
    float var = t2 * (1.f / 256.f) - mean * mean;
    stats[0] = mean;
    stats[1] = rsqrtf(var + 1e-5f);
  }
  __syncthreads();
  float v = (r - stats[0]) * stats[1] * ldf(g, gOff + tid, f) + ldf(bta, btaOff + tid, f);
  x[row * D_ + tid] = v;
}

// ---------------------------------------------------------------------------
// Head for one chunk: b_global = b0 + blockIdx.x; cls row from g_ws.
// out: decision_logits (512*4) then action_pred (512); dtype per flag.
// ---------------------------------------------------------------------------
__global__ __launch_bounds__(256) void head_kernel(
    const void* dg, const void* dbt, const void* dW, const void* dbias,
    const void* ag, const void* abt, const void* aW, const void* abias,
    void* out, int b0)
{
  const int f = g_f32flag;
  const float* x = g_ws + XOFF;
  int bl = blockIdx.x;
  int bg = b0 + bl;
  int tid = threadIdx.x;
  float c = x[(size_t)bl * S_ * D_ + tid];
  float s1 = c, s2 = c * c;
#pragma unroll
  for (int off = 32; off > 0; off >>= 1) {
    s1 += __shfl_down(s1, off, 64);
    s2 += __shfl_down(s2, off, 64);
  }
  __shared__ float ws1[4], ws2[4], stats[2];
  __shared__ float lnD[256], lnA[256];
  int wid = tid >> 6, lane = tid & 63;
  if (lane == 0) { ws1[wid] = s1; ws2[wid] = s2; }
  __syncthreads();
  if (tid == 0) {
    float t1 = ws1[0] + ws1[1] + ws1[2] + ws1[3];
    float t2 = ws2[0] + ws2[1] + ws2[2] + ws2[3];
    float mean = t1 * (1.f / 256.f);
    float var = t2 * (1.f / 256.f) - mean * mean;
    stats[0] = mean;
    stats[1] = rsqrtf(var + 1e-5f);
  }
  __syncthreads();
  float n = (c - stats[0]) * stats[1];
  lnD[tid] = n * ldf(dg, tid, f) + ldf(dbt, tid, f);
  lnA[tid] = n * ldf(ag, tid, f) + ldf(abt, tid, f);
  __syncthreads();
  if (tid < NC_) {
    float acc = ldf(dbias, tid, f);
    for (int k = 0; k < D_; k++) acc += lnD[k] * ldf(dW, k * NC_ + tid, f);
    if (f) ((float*)out)[bg * NC_ + tid] = acc;
    else   ((bf16*)out)[bg * NC_ + tid] = __float2bfloat16(acc);
  } else if (tid == 8) {
    float acc = ldf(abias, 0, f);
    for (int k = 0; k < D_; k++) acc += lnA[k] * ldf(aW, k, f);
    if (f) ((float*)out)[B_ * NC_ + bg] = acc;
    else   ((bf16*)out)[B_ * NC_ + bg] = __float2bfloat16(acc);
  }
}

// ---------------------------------------------------------------------------
extern "C" void kernel_launch(void* const* d_in, const int* in_sizes, int n_in,
                              void* d_out, int out_size, void* d_ws, size_t ws_size,
                              hipStream_t stream)
{
  (void)in_sizes; (void)out_size; (void)d_ws; (void)ws_size;
  if (n_in < 34) return;
  const int* token_types  = (const int*)d_in[0];
  const int* decision_ids = (const int*)d_in[1];

  const int R = RROWS;        // 19328 rows/chunk
  const int MB = R / 64;      // 302
  const int nchunk = B_ / RBC;

  probe_kernel<<<1, 256, 0, stream>>>(d_in[12]);   // pos_embed

  for (int c = 0; c < nchunk; c++) {
    const int b0 = c * RBC;
    const int row0 = b0 * S_;
    embed_kernel<<<R, 256, 0, stream>>>(token_types, decision_ids,
        d_in[2], d_in[3], d_in[4], d_in[5], d_in[6], d_in[7], d_in[8],
        d_in[9], d_in[10], d_in[11], d_in[12], d_in[13], row0);
    for (int i = 0; i < DEPTH_; i++) {
      gemm_ws<<<dim3(768 / 64, MB), 256, 0, stream>>>(XOFF,
          d_in[14], (size_t)i * D_ * 768, d_in[15], (size_t)i * 768,
          C1OFF, R, 768, D_, 0);
      attn_kernel<<<RBC * H_, 192, 0, stream>>>();
      gemm_ws<<<dim3(D_ / 64, MB), 256, 0, stream>>>(C2OFF,
          d_in[16], (size_t)i * D_ * D_, d_in[17], (size_t)i * D_,
          C1OFF, R, D_, D_, 0);                       // y1 -> c1 (qkv dead)
      resln_kernel<<<R, 256, 0, stream>>>(C1OFF,
          d_in[18], (size_t)i * D_, d_in[19], (size_t)i * D_);
      gemm_ws<<<dim3(FF_ / 64, MB), 256, 0, stream>>>(XOFF,
          d_in[22], (size_t)i * D_ * FF_, d_in[23], (size_t)i * FF_,
          C1OFF, R, FF_, D_, 1);
      gemm_ws<<<dim3(D_ / 64, MB), 256, 0, stream>>>(C1OFF,
          d_in[24], (size_t)i * FF_ * D_, d_in[25], (size_t)i * D_,
          C2OFF, R, D_, FF_, 0);                      // y2 -> c2
      resln_kernel<<<R, 256, 0, stream>>>(C2OFF,
          d_in[20], (size_t)i * D_, d_in[21], (size_t)i * D_);
    }
    head_kernel<<<RBC, 256, 0, stream>>>(d_in[26], d_in[27], d_in[28], d_in[29],
        d_in[30], d_in[31], d_in[32], d_in[33], d_out, b0);
  }
}

// Round 6
// 4690.735 us; speedup vs baseline: 3.7167x; 3.7167x over previous
//
#include <hip/hip_runtime.h>
#include <hip/hip_bf16.h>

typedef __hip_bfloat16 bf16;
typedef unsigned short u16;
typedef __attribute__((ext_vector_type(8))) short s16x8;   // 8 bf16 (4 VGPRs) MFMA frag
typedef __attribute__((ext_vector_type(4))) float f32x4;   // MFMA accumulator

#define B_ 512
#define T_ 150
#define S_ 151
#define D_ 256
#define H_ 8
#define HD_ 32
#define FF_ 1024
#define NC_ 4
#define DEPTH_ 6
#define MTOT 77312            // B_*S_ = 128 * 604
#define MT128 (MTOT / 128)    // 604

// bf16 workspace regions (elements):
#define XOFF 0
#define C1OFF (MTOT * D_)               // x: MTOT*256
#define C2OFF (C1OFF + MTOT * FF_)      // c1: MTOT*1024 (qkv / ffn / y reuse)
#define WSELEMS (C2OFF + MTOT * D_)     // c2: MTOT*256   -> total 118,751,232 u16 = 237.5 MB

// Transposed bf16 weights Wt[N][K], all layers, rebuilt每call:
#define QKVT_OFF 0
#define OUTT_OFF (QKVT_OFF + DEPTH_ * D_ * 768)    // 1,179,648
#define FFN1T_OFF (OUTT_OFF + DEPTH_ * D_ * D_)    // +393,216
#define FFN2T_OFF (FFN1T_OFF + DEPTH_ * D_ * FF_)  // +1,572,864
#define WTELEMS (FFN2T_OFF + DEPTH_ * FF_ * D_)    // 4,718,592 = 9.4 MB

// Static device memory (d_ws proved unusable rounds 1-3). Everything read in
// a call is written earlier in the SAME call.
__device__ __align__(16) u16 g_ws[WSELEMS];
__device__ __align__(16) u16 g_wt[WTELEMS];
__device__ int g_f32flag;   // 1 => external buffers f32, 0 => bf16

__device__ __forceinline__ float ldf(const void* p, size_t i, int f) {
  return f ? ((const float*)p)[i] : __bfloat162float(((const bf16*)p)[i]);
}
__device__ __forceinline__ float b2f(u16 u) {
  union { unsigned int i; float f; } v; v.i = ((unsigned int)u) << 16; return v.f;
}
__device__ __forceinline__ u16 f2b(float x) {
  bf16 h = __float2bfloat16(x);
  return *reinterpret_cast<u16*>(&h);
}

// ---------------------------------------------------------------------------
// Dtype probe on pos_embed (38656 elems ~N(0,0.02^2)) viewed as 16-bit words.
// f32 data: junk low halves (exp>=141) or all-even-words-zero. Deterministic.
// ---------------------------------------------------------------------------
#define PROBE_N 38656
__global__ __launch_bounds__(256) void probe_kernel(const void* pe)
{
  const u16* w = (const u16*)pe;
  int susp = 0, zeroEven = 0;
  for (int k = threadIdx.x; k < PROBE_N; k += 256) {
    u16 u = w[k];
    int ex = (u >> 7) & 0xFF;
    if (ex >= 141) susp++;
    if ((k & 1) == 0 && (u & 0x7FFF) == 0) zeroEven++;
  }
  __shared__ int s_susp, s_zero;
  if (threadIdx.x == 0) { s_susp = 0; s_zero = 0; }
  __syncthreads();
  atomicAdd(&s_susp, susp);
  atomicAdd(&s_zero, zeroEven);
  __syncthreads();
  if (threadIdx.x == 0)
    g_f32flag = (s_susp > 0 || s_zero >= ((PROBE_N / 2) * 9) / 10) ? 1 : 0;
}

// ---------------------------------------------------------------------------
// Weight transpose+convert: Wt[l][n][k] = W[l][k][n] as bf16. Coalesced reads.
// ---------------------------------------------------------------------------
__global__ __launch_bounds__(256) void wtrans_kernel(const void* src, int dstOff,
                                                     int K, int N, int total)
{
  const int f = g_f32flag;
  int idx = blockIdx.x * 256 + threadIdx.x;
  if (idx >= total) return;
  int kn = K * N;
  int l = idx / kn;
  int r = idx - l * kn;
  int k = r / N;
  int n = r - k * N;
  g_wt[dstOff + (size_t)l * kn + (size_t)n * K + k] = f2b(ldf(src, idx, f));
}

// ---------------------------------------------------------------------------
// Embedding: row = blockIdx.x (full batch), writes bf16 x.
// ---------------------------------------------------------------------------
__global__ __launch_bounds__(256) void embed_kernel(
    const int* __restrict__ tt, const int* __restrict__ dids,
    const void* av, const void* dv, const void* vv,
    const void* aW, const void* ab, const void* dW, const void* db,
    const void* vW, const void* vb, const void* table, const void* pos,
    const void* cls)
{
  const int f = g_f32flag;
  u16* x = g_ws + XOFF;
  int row = blockIdx.x;
  int d = threadIdx.x;
  int b = row / S_;
  int s = row - b * S_;
  float val;
  if (s == 0) {
    val = ldf(cls, d, f);
  } else {
    int t = s - 1;
    int idx = b * T_ + t;
    int ty = tt[idx];
    if (ty == 0) {
      val = ldf(av, idx, f) * ldf(aW, d, f) + ldf(ab, d, f);
    } else if (ty == 1) {
      float acc = ldf(db, d, f) + ldf(vb, d, f);
#pragma unroll
      for (int i = 0; i < 10; i++) acc += ldf(dv, (size_t)idx * 10 + i, f) * ldf(dW, i * D_ + d, f);
#pragma unroll
      for (int i = 0; i < 3; i++) acc += ldf(vv, (size_t)idx * 3 + i, f) * ldf(vW, i * D_ + d, f);
      val = acc;
    } else if (ty == 2) {
      int did = dids[idx] & (NC_ - 1);
      val = ldf(table, (size_t)did * D_ + d, f);
    } else {
      val = 0.f;
    }
  }
  val += ldf(pos, s * D_ + d, f);
  x[(size_t)row * D_ + d] = f2b(val);
}

// ---------------------------------------------------------------------------
// MFMA GEMM: C[M,N] = A[M,K] @ W[K,N] + bias (opt relu), all bf16 in ws,
// f32 accumulate. Weights pre-transposed: Bt[N][K] in g_wt.
// 128x128 tile, BK=32, 256 thr = 4 waves, each wave a 64x64 quadrant
// (4x4 grid of 16x16x32 MFMA). M=77312 (=128*604), N mult of 128.
// ---------------------------------------------------------------------------
__global__ __launch_bounds__(256) void gemm_mfma(
    int aOff, int wtOff, const void* bias, size_t bOff,
    int cOff, int N, int K, int relu)
{
  const int f = g_f32flag;
  const u16* A = g_ws + aOff;
  const u16* Bt = g_wt + wtOff;
  u16* C = g_ws + cOff;
  __shared__ u16 As[128 * 32];
  __shared__ u16 Bs[128 * 32];
  const int tid = threadIdx.x;
  const int bm = blockIdx.y, bn = blockIdx.x;
  const int lane = tid & 63, wid = tid >> 6;
  const int wm = (wid >> 1) * 64, wn = (wid & 1) * 64;
  const int frow = lane & 15, fk = (lane >> 4) * 8;

  // Staging: thread -> (row = tid>>1, 16-col half = (tid&1)*16), 2x16B each.
  const int srow = tid >> 1;
  const int scol = (tid & 1) * 16;
  const u16* Agp = A + (size_t)(bm * 128 + srow) * K + scol;
  const u16* Bgp = Bt + (size_t)(bn * 128 + srow) * K + scol;
  u16* Asp = &As[srow * 32 + scol];
  u16* Bsp = &Bs[srow * 32 + scol];

  f32x4 acc[4][4] = {};

  for (int kt = 0; kt < K; kt += 32) {
    s16x8 a0 = *(const s16x8*)(Agp + kt);
    s16x8 a1 = *(const s16x8*)(Agp + kt + 8);
    s16x8 b0 = *(const s16x8*)(Bgp + kt);
    s16x8 b1 = *(const s16x8*)(Bgp + kt + 8);
    if (kt) __syncthreads();            // protect LDS from prior iter's readers
    *(s16x8*)Asp = a0;
    *(s16x8*)(Asp + 8) = a1;
    *(s16x8*)Bsp = b0;
    *(s16x8*)(Bsp + 8) = b1;
    __syncthreads();
    s16x8 af[4], bfr[4];
#pragma unroll
    for (int t = 0; t < 4; t++) {
      af[t]  = *(const s16x8*)&As[(wm + t * 16 + frow) * 32 + fk];
      bfr[t] = *(const s16x8*)&Bs[(wn + t * 16 + frow) * 32 + fk];
    }
#pragma unroll
    for (int mt = 0; mt < 4; mt++)
#pragma unroll
      for (int nt = 0; nt < 4; nt++)
        acc[mt][nt] = __builtin_amdgcn_mfma_f32_16x16x32_bf16(af[mt], bfr[nt], acc[mt][nt], 0, 0, 0);
  }

  // Epilogue. C/D layout: col = lane&15, row = (lane>>4)*4 + reg.
  const int ccol = lane & 15;
  const int crow0 = (lane >> 4) * 4;
  float bv[4];
#pragma unroll
  for (int nt = 0; nt < 4; nt++)
    bv[nt] = ldf(bias, bOff + (size_t)(bn * 128 + wn + nt * 16 + ccol), f);
#pragma unroll
  for (int mt = 0; mt < 4; mt++) {
#pragma unroll
    for (int nt = 0; nt < 4; nt++) {
      int colg = bn * 128 + wn + nt * 16 + ccol;
#pragma unroll
      for (int r = 0; r < 4; r++) {
        int rowg = bm * 128 + wm + mt * 16 + crow0 + r;
        float v = acc[mt][nt][r] + bv[nt];
        if (relu) v = fmaxf(v, 0.f);
        C[(size_t)rowg * N + colg] = f2b(v);
      }
    }
  }
}

// ---------------------------------------------------------------------------
// Attention: one block per (b,h); qkv (bf16) at g_ws+C1OFF (stride 768,
// [q|k|v]); out (bf16) at g_ws+C2OFF (stride 256). Internal f32.
// ---------------------------------------------------------------------------
__global__ __launch_bounds__(192) void attn_kernel()
{
  const u16* qkv = g_ws + C1OFF;
  u16* o = g_ws + C2OFF;
  __shared__ float Ks[S_ * HD_];
  __shared__ float Vs[S_ * HD_];
  int bh = blockIdx.x;
  int b = bh >> 3, h = bh & 7;
  int tid = threadIdx.x;
  const u16* base = qkv + (size_t)b * S_ * 768;
  for (int idx = tid; idx < S_ * HD_; idx += 192) {
    int j = idx >> 5, d = idx & 31;
    Ks[idx] = b2f(base[(size_t)j * 768 + 256 + h * 32 + d]);
    Vs[idx] = b2f(base[(size_t)j * 768 + 512 + h * 32 + d]);
  }
  __syncthreads();
  if (tid < S_) {
    const float scale = 0.17677669529663687f;  // 1/sqrt(32)
    float q[32];
    const u16* qp = base + (size_t)tid * 768 + h * 32;
#pragma unroll
    for (int d = 0; d < 32; d++) q[d] = b2f(qp[d]) * scale;
    float m = -1e30f, l = 0.f;
    float oa[32];
#pragma unroll
    for (int d = 0; d < 32; d++) oa[d] = 0.f;
    for (int j = 0; j < S_; j++) {
      const float* kp = &Ks[j * 32];
      float s = 0.f;
#pragma unroll
      for (int d = 0; d < 32; d++) s += q[d] * kp[d];
      float nm = fmaxf(m, s);
      float alpha = __expf(m - nm);
      float p = __expf(s - nm);
      l = l * alpha + p;
      const float* vp = &Vs[j * 32];
#pragma unroll
      for (int d = 0; d < 32; d++) oa[d] = oa[d] * alpha + p * vp[d];
      m = nm;
    }
    float inv = 1.f / l;
    u16* op = o + (size_t)(b * S_ + tid) * D_ + h * 32;
#pragma unroll
    for (int d = 0; d < 32; d++) op[d] = f2b(oa[d] * inv);
  }
}

// ---------------------------------------------------------------------------
// x = LN(x + y) * g + b over D=256 (bf16 storage, f32 math).
// ---------------------------------------------------------------------------
__global__ __launch_bounds__(256) void resln_kernel(int yOff,
    const void* g, size_t gOff, const void* bta, size_t btaOff)
{
  const int f = g_f32flag;
  u16* x = g_ws + XOFF;
  const u16* y = g_ws + yOff;
  size_t row = blockIdx.x;
  int tid = threadIdx.x;
  float r = b2f(x[row * D_ + tid]) + b2f(y[row * D_ + tid]);
  float s1 = r, s2 = r * r;
#pragma unroll
  for (int off = 32; off > 0; off >>= 1) {
    s1 += __shfl_down(s1, off, 64);
    s2 += __shfl_down(s2, off, 64);
  }
  __shared__ float ws1[4], ws2[4], stats[2];
  int wid = tid >> 6, lane = tid & 63;
  if (lane == 0) { ws1[wid] = s1; ws2[wid] = s2; }
  __syncthreads();
  if (tid == 0) {
    float t1 = ws1[0] + ws1[1] + ws1[2] + ws1[3];
    float t2 = ws2[0] + ws2[1] + ws2[2] + ws2[3];
    float mean = t1 * (1.f / 256.f);
    float var = t2 * (1.f / 256.f) - mean * mean;
    stats[0] = mean;
    stats[1] = rsqrtf(var + 1e-5f);
  }
  __syncthreads();
  float v = (r - stats[0]) * stats[1] * ldf(g, gOff + tid, f) + ldf(bta, btaOff + tid, f);
  x[row * D_ + tid] = f2b(v);
}

// ---------------------------------------------------------------------------
// Head: cls row -> two LNs (shared stats) -> two tiny matvecs.
// out: decision_logits (512*4) then action_pred (512); dtype per flag.
// ---------------------------------------------------------------------------
__global__ __launch_bounds__(256) void head_kernel(
    const void* dg, const void* dbt, const void* dW, const void* dbias,
    const void* ag, const void* abt, const void* aW, const void* abias,
    void* out)
{
  const int f = g_f32flag;
  const u16* x = g_ws + XOFF;
  int bg = blockIdx.x;
  int tid = threadIdx.x;
  float c = b2f(x[(size_t)bg * S_ * D_ + tid]);
  float s1 = c, s2 = c * c;
#pragma unroll
  for (int off = 32; off > 0; off >>= 1) {
    s1 += __shfl_down(s1, off, 64);
    s2 += __shfl_down(s2, off, 64);
  }
  __shared__ float ws1[4], ws2[4], stats[2];
  __shared__ float lnD[256], lnA[256];
  int wid = tid >> 6, lane = tid & 63;
  if (lane == 0) { ws1[wid] = s1; ws2[wid] = s2; }
  __syncthreads();
  if (tid == 0) {
    float t1 = ws1[0] + ws1[1] + ws1[2] + ws1[3];
    float t2 = ws2[0] + ws2[1] + ws2[2] + ws2[3];
    float mean = t1 * (1.f / 256.f);
    float var = t2 * (1.f / 256.f) - mean * mean;
    stats[0] = mean;
    stats[1] = rsqrtf(var + 1e-5f);
  }
  __syncthreads();
  float n = (c - stats[0]) * stats[1];
  lnD[tid] = n * ldf(dg, tid, f) + ldf(dbt, tid, f);
  lnA[tid] = n * ldf(ag, tid, f) + ldf(abt, tid, f);
  __syncthreads();
  if (tid < NC_) {
    float acc = ldf(dbias, tid, f);
    for (int k = 0; k < D_; k++) acc += lnD[k] * ldf(dW, k * NC_ + tid, f);
    if (f) ((float*)out)[bg * NC_ + tid] = acc;
    else   ((bf16*)out)[bg * NC_ + tid] = __float2bfloat16(acc);
  } else if (tid == 8) {
    float acc = ldf(abias, 0, f);
    for (int k = 0; k < D_; k++) acc += lnA[k] * ldf(aW, k, f);
    if (f) ((float*)out)[B_ * NC_ + bg] = acc;
    else   ((bf16*)out)[B_ * NC_ + bg] = __float2bfloat16(acc);
  }
}

// ---------------------------------------------------------------------------
extern "C" void kernel_launch(void* const* d_in, const int* in_sizes, int n_in,
                              void* d_out, int out_size, void* d_ws, size_t ws_size,
                              hipStream_t stream)
{
  (void)in_sizes; (void)out_size; (void)d_ws; (void)ws_size;
  if (n_in < 34) return;
  const int* token_types  = (const int*)d_in[0];
  const int* decision_ids = (const int*)d_in[1];

  probe_kernel<<<1, 256, 0, stream>>>(d_in[12]);   // pos_embed

  // Transposed bf16 weight slabs (once per call).
  wtrans_kernel<<<(DEPTH_ * D_ * 768 + 255) / 256, 256, 0, stream>>>(
      d_in[14], QKVT_OFF, D_, 768, DEPTH_ * D_ * 768);
  wtrans_kernel<<<(DEPTH_ * D_ * D_ + 255) / 256, 256, 0, stream>>>(
      d_in[16], OUTT_OFF, D_, D_, DEPTH_ * D_ * D_);
  wtrans_kernel<<<(DEPTH_ * D_ * FF_ + 255) / 256, 256, 0, stream>>>(
      d_in[22], FFN1T_OFF, D_, FF_, DEPTH_ * D_ * FF_);
  wtrans_kernel<<<(DEPTH_ * FF_ * D_ + 255) / 256, 256, 0, stream>>>(
      d_in[24], FFN2T_OFF, FF_, D_, DEPTH_ * FF_ * D_);

  embed_kernel<<<MTOT, 256, 0, stream>>>(token_types, decision_ids,
      d_in[2], d_in[3], d_in[4], d_in[5], d_in[6], d_in[7], d_in[8],
      d_in[9], d_in[10], d_in[11], d_in[12], d_in[13]);

  for (int i = 0; i < DEPTH_; i++) {
    gemm_mfma<<<dim3(768 / 128, MT128), 256, 0, stream>>>(XOFF,
        QKVT_OFF + i * D_ * 768, d_in[15], (size_t)i * 768, C1OFF, 768, D_, 0);
    attn_kernel<<<B_ * H_, 192, 0, stream>>>();
    gemm_mfma<<<dim3(D_ / 128, MT128), 256, 0, stream>>>(C2OFF,
        OUTT_OFF + i * D_ * D_, d_in[17], (size_t)i * D_, C1OFF, D_, D_, 0);   // y1 -> c1
    resln_kernel<<<MTOT, 256, 0, stream>>>(C1OFF,
        d_in[18], (size_t)i * D_, d_in[19], (size_t)i * D_);
    gemm_mfma<<<dim3(FF_ / 128, MT128), 256, 0, stream>>>(XOFF,
        FFN1T_OFF + i * D_ * FF_, d_in[23], (size_t)i * FF_, C1OFF, FF_, D_, 1);
    gemm_mfma<<<dim3(D_ / 128, MT128), 256, 0, stream>>>(C1OFF,
        FFN2T_OFF + i * FF_ * D_, d_in[25], (size_t)i * D_, C2OFF, D_, FF_, 0); // y2 -> c2
    resln_kernel<<<MTOT, 256, 0, stream>>>(C2OFF,
        d_in[20], (size_t)i * D_, d_in[21], (size_t)i * D_);
  }
  head_kernel<<<B_, 256, 0, stream>>>(d_in[26], d_in[27], d_in[28], d_in[29],
      d_in[30], d_in[31], d_in[32], d_in[33], d_out);
}

// Round 7
// 3555.239 us; speedup vs baseline: 4.9037x; 1.3194x over previous
//
#include <hip/hip_runtime.h>
#include <hip/hip_bf16.h>

typedef __hip_bfloat16 bf16;
typedef unsigned short u16;
typedef __attribute__((ext_vector_type(8))) short s16x8;   // 8 bf16 (4 VGPRs) MFMA frag
typedef __attribute__((ext_vector_type(4))) float f32x4;   // MFMA accumulator

#define B_ 512
#define T_ 150
#define S_ 151
#define D_ 256
#define H_ 8
#define HD_ 32
#define FF_ 1024
#define NC_ 4
#define DEPTH_ 6
#define MTOT 77312            // B_*S_ = 128 * 604
#define MT128 (MTOT / 128)    // 604

// bf16 workspace regions (elements):
#define XOFF 0
#define C1OFF (MTOT * D_)               // x: MTOT*256
#define C2OFF (C1OFF + MTOT * FF_)      // c1: MTOT*1024 (qkv / ffn / y reuse)
#define WSELEMS (C2OFF + MTOT * D_)     // c2: MTOT*256

// Transposed bf16 weights Wt[N][K], all layers, rebuilt per call:
#define QKVT_OFF 0
#define OUTT_OFF (QKVT_OFF + DEPTH_ * D_ * 768)
#define FFN1T_OFF (OUTT_OFF + DEPTH_ * D_ * D_)
#define FFN2T_OFF (FFN1T_OFF + DEPTH_ * D_ * FF_)
#define WTELEMS (FFN2T_OFF + DEPTH_ * FF_ * D_)    // 9.4 MB

// Static device memory (d_ws proved unusable rounds 1-3). Everything read in
// a call is written earlier in the SAME call.
__device__ __align__(16) u16 g_ws[WSELEMS];
__device__ __align__(16) u16 g_wt[WTELEMS];
__device__ int g_f32flag;   // 1 => external buffers f32, 0 => bf16

__device__ __forceinline__ float ldf(const void* p, size_t i, int f) {
  return f ? ((const float*)p)[i] : __bfloat162float(((const bf16*)p)[i]);
}
__device__ __forceinline__ float b2f(u16 u) {
  union { unsigned int i; float f; } v; v.i = ((unsigned int)u) << 16; return v.f;
}
__device__ __forceinline__ u16 f2b(float x) {
  bf16 h = __float2bfloat16(x);
  return *reinterpret_cast<u16*>(&h);
}

// ---------------------------------------------------------------------------
// Dtype probe on pos_embed (38656 elems ~N(0,0.02^2)) viewed as 16-bit words.
// ---------------------------------------------------------------------------
#define PROBE_N 38656
__global__ __launch_bounds__(256) void probe_kernel(const void* pe)
{
  const u16* w = (const u16*)pe;
  int susp = 0, zeroEven = 0;
  for (int k = threadIdx.x; k < PROBE_N; k += 256) {
    u16 u = w[k];
    int ex = (u >> 7) & 0xFF;
    if (ex >= 141) susp++;
    if ((k & 1) == 0 && (u & 0x7FFF) == 0) zeroEven++;
  }
  __shared__ int s_susp, s_zero;
  if (threadIdx.x == 0) { s_susp = 0; s_zero = 0; }
  __syncthreads();
  atomicAdd(&s_susp, susp);
  atomicAdd(&s_zero, zeroEven);
  __syncthreads();
  if (threadIdx.x == 0)
    g_f32flag = (s_susp > 0 || s_zero >= ((PROBE_N / 2) * 9) / 10) ? 1 : 0;
}

// ---------------------------------------------------------------------------
// Weight transpose+convert: Wt[l][n][k] = W[l][k][n] as bf16.
// ---------------------------------------------------------------------------
__global__ __launch_bounds__(256) void wtrans_kernel(const void* src, int dstOff,
                                                     int K, int N, int total)
{
  const int f = g_f32flag;
  int idx = blockIdx.x * 256 + threadIdx.x;
  if (idx >= total) return;
  int kn = K * N;
  int l = idx / kn;
  int r = idx - l * kn;
  int k = r / N;
  int n = r - k * N;
  g_wt[dstOff + (size_t)l * kn + (size_t)n * K + k] = f2b(ldf(src, idx, f));
}

// ---------------------------------------------------------------------------
// Embedding: row = blockIdx.x, writes bf16 x.
// ---------------------------------------------------------------------------
__global__ __launch_bounds__(256) void embed_kernel(
    const int* __restrict__ tt, const int* __restrict__ dids,
    const void* av, const void* dv, const void* vv,
    const void* aW, const void* ab, const void* dW, const void* db,
    const void* vW, const void* vb, const void* table, const void* pos,
    const void* cls)
{
  const int f = g_f32flag;
  u16* x = g_ws + XOFF;
  int row = blockIdx.x;
  int d = threadIdx.x;
  int b = row / S_;
  int s = row - b * S_;
  float val;
  if (s == 0) {
    val = ldf(cls, d, f);
  } else {
    int t = s - 1;
    int idx = b * T_ + t;
    int ty = tt[idx];
    if (ty == 0) {
      val = ldf(av, idx, f) * ldf(aW, d, f) + ldf(ab, d, f);
    } else if (ty == 1) {
      float acc = ldf(db, d, f) + ldf(vb, d, f);
#pragma unroll
      for (int i = 0; i < 10; i++) acc += ldf(dv, (size_t)idx * 10 + i, f) * ldf(dW, i * D_ + d, f);
#pragma unroll
      for (int i = 0; i < 3; i++) acc += ldf(vv, (size_t)idx * 3 + i, f) * ldf(vW, i * D_ + d, f);
      val = acc;
    } else if (ty == 2) {
      int did = dids[idx] & (NC_ - 1);
      val = ldf(table, (size_t)did * D_ + d, f);
    } else {
      val = 0.f;
    }
  }
  val += ldf(pos, s * D_ + d, f);
  x[(size_t)row * D_ + d] = f2b(val);
}

// ---------------------------------------------------------------------------
// MFMA GEMM: C[M,N] = A[M,K] @ W[K,N] + bias (opt relu). Bt[N][K] in g_wt.
// 128x128 tile, BK=32, 4 waves x 64x64 quadrant of 16x16x32 MFMAs.
// ---------------------------------------------------------------------------
__global__ __launch_bounds__(256) void gemm_mfma(
    int aOff, int wtOff, const void* bias, size_t bOff,
    int cOff, int N, int K, int relu)
{
  const int f = g_f32flag;
  const u16* A = g_ws + aOff;
  const u16* Bt = g_wt + wtOff;
  u16* C = g_ws + cOff;
  __shared__ u16 As[128 * 32];
  __shared__ u16 Bs[128 * 32];
  const int tid = threadIdx.x;
  const int bm = blockIdx.y, bn = blockIdx.x;
  const int lane = tid & 63, wid = tid >> 6;
  const int wm = (wid >> 1) * 64, wn = (wid & 1) * 64;
  const int frow = lane & 15, fk = (lane >> 4) * 8;

  const int srow = tid >> 1;
  const int scol = (tid & 1) * 16;
  const u16* Agp = A + (size_t)(bm * 128 + srow) * K + scol;
  const u16* Bgp = Bt + (size_t)(bn * 128 + srow) * K + scol;
  u16* Asp = &As[srow * 32 + scol];
  u16* Bsp = &Bs[srow * 32 + scol];

  f32x4 acc[4][4] = {};

  for (int kt = 0; kt < K; kt += 32) {
    s16x8 a0 = *(const s16x8*)(Agp + kt);
    s16x8 a1 = *(const s16x8*)(Agp + kt + 8);
    s16x8 b0 = *(const s16x8*)(Bgp + kt);
    s16x8 b1 = *(const s16x8*)(Bgp + kt + 8);
    if (kt) __syncthreads();
    *(s16x8*)Asp = a0;
    *(s16x8*)(Asp + 8) = a1;
    *(s16x8*)Bsp = b0;
    *(s16x8*)(Bsp + 8) = b1;
    __syncthreads();
    s16x8 af[4], bfr[4];
#pragma unroll
    for (int t = 0; t < 4; t++) {
      af[t]  = *(const s16x8*)&As[(wm + t * 16 + frow) * 32 + fk];
      bfr[t] = *(const s16x8*)&Bs[(wn + t * 16 + frow) * 32 + fk];
    }
#pragma unroll
    for (int mt = 0; mt < 4; mt++)
#pragma unroll
      for (int nt = 0; nt < 4; nt++)
        acc[mt][nt] = __builtin_amdgcn_mfma_f32_16x16x32_bf16(af[mt], bfr[nt], acc[mt][nt], 0, 0, 0);
  }

  const int ccol = lane & 15;
  const int crow0 = (lane >> 4) * 4;
  float bv[4];
#pragma unroll
  for (int nt = 0; nt < 4; nt++)
    bv[nt] = ldf(bias, bOff + (size_t)(bn * 128 + wn + nt * 16 + ccol), f);
#pragma unroll
  for (int mt = 0; mt < 4; mt++) {
#pragma unroll
    for (int nt = 0; nt < 4; nt++) {
      int colg = bn * 128 + wn + nt * 16 + ccol;
#pragma unroll
      for (int r = 0; r < 4; r++) {
        int rowg = bm * 128 + wm + mt * 16 + crow0 + r;
        float v = acc[mt][nt][r] + bv[nt];
        if (relu) v = fmaxf(v, 0.f);
        C[(size_t)rowg * N + colg] = f2b(v);
      }
    }
  }
}

// ---------------------------------------------------------------------------
// MFMA attention, non-flash (S=151 -> padded 160). One block per (b,h),
// 256 thr = 4 waves. S = Q@K^T: K stored [key][d] == B-operand [n][k] layout
// (no transpose). Full-row softmax in C-layout regs (row = quad*4+r, reduced
// across the 16 lanes of the quad). P -> per-wave LDS (C->A layout), then
// P@V with Vt[d][j]. 10 m-tiles over 4 waves in 3 rounds, unconditional
// barriers. LDS rows padded (40/168 u16) -> worst 2-way bank alias (free).
// ---------------------------------------------------------------------------
#define SP 160
#define KLD 40
#define VLD 168
#define PLD 168

__global__ __launch_bounds__(256) void attn_kernel()
{
  const u16* qkv = g_ws + C1OFF;
  u16* o = g_ws + C2OFF;
  __shared__ __align__(16) u16 Ks[SP * KLD];        // [j][d]  12800 B
  __shared__ __align__(16) u16 Vt[HD_ * VLD];       // [d][j]  10752 B
  __shared__ __align__(16) u16 Ps[4][16 * PLD];     // per-wave P tile  21504 B
  int bh = blockIdx.x;
  int b = bh >> 3, h = bh & 7;
  int tid = threadIdx.x;
  int lane = tid & 63, wid = tid >> 6;
  const u16* base = qkv + (size_t)b * S_ * 768;

  // Stage K (coalesced: consecutive tid -> consecutive d).
  for (int idx = tid; idx < SP * HD_; idx += 256) {
    int j = idx >> 5, d = idx & 31;
    Ks[j * KLD + d] = (j < S_) ? base[(size_t)j * 768 + 256 + h * 32 + d] : (u16)0;
  }
  // Stage V transposed (coalesced global read, transposed LDS write).
  for (int idx = tid; idx < SP * HD_; idx += 256) {
    int j = idx >> 5, d = idx & 31;
    Vt[d * VLD + j] = (j < S_) ? base[(size_t)j * 768 + 512 + h * 32 + d] : (u16)0;
  }
  __syncthreads();

  const int frow = lane & 15;
  const int quad = lane >> 4;
  const int fk = quad * 8;
  const float scale = 0.17677669529663687f;  // 1/sqrt(32)

  for (int round = 0; round < 3; round++) {
    int mt = round * 4 + wid;
    bool active = (mt < 10);
    if (active) {
      // A-frag: Q[qrow][fk..fk+8) straight from global (each row read once).
      int qrow = mt * 16 + frow;
      s16x8 aq = {0, 0, 0, 0, 0, 0, 0, 0};
      if (qrow < S_) aq = *(const s16x8*)(base + (size_t)qrow * 768 + h * 32 + fk);
      f32x4 sacc[10];
#pragma unroll
      for (int nt = 0; nt < 10; nt++) {
        s16x8 bk = *(const s16x8*)&Ks[(nt * 16 + frow) * KLD + fk];
        f32x4 z = {0.f, 0.f, 0.f, 0.f};
        sacc[nt] = __builtin_amdgcn_mfma_f32_16x16x32_bf16(aq, bk, z, 0, 0, 0);
      }
      // Scale + mask cols >= S_ (C-layout: col = lane&15 within n-tile).
#pragma unroll
      for (int nt = 0; nt < 10; nt++) {
        int colg = nt * 16 + frow;
        float msk = (colg < S_) ? 1.f : 0.f;
#pragma unroll
        for (int r = 0; r < 4; r++)
          sacc[nt][r] = msk ? sacc[nt][r] * scale : -1e30f;
      }
      // Per-row softmax: rows live across the 16 lanes of a quad.
#pragma unroll
      for (int r = 0; r < 4; r++) {
        float mx = -1e30f;
#pragma unroll
        for (int nt = 0; nt < 10; nt++) mx = fmaxf(mx, sacc[nt][r]);
#pragma unroll
        for (int m = 1; m < 16; m <<= 1) mx = fmaxf(mx, __shfl_xor(mx, m, 64));
        float sm = 0.f;
#pragma unroll
        for (int nt = 0; nt < 10; nt++) {
          float p = __expf(sacc[nt][r] - mx);
          sacc[nt][r] = p;
          sm += p;
        }
#pragma unroll
        for (int m = 1; m < 16; m <<= 1) sm += __shfl_xor(sm, m, 64);
        float inv = 1.f / sm;
#pragma unroll
        for (int nt = 0; nt < 10; nt++) sacc[nt][r] *= inv;
      }
      // C-layout -> A-layout via per-wave LDS (bf16).
#pragma unroll
      for (int nt = 0; nt < 10; nt++)
#pragma unroll
        for (int r = 0; r < 4; r++)
          Ps[wid][(quad * 4 + r) * PLD + nt * 16 + frow] = f2b(sacc[nt][r]);
    }
    __syncthreads();
    if (active) {
      f32x4 oacc[2] = {};
#pragma unroll
      for (int ks = 0; ks < 5; ks++) {
        s16x8 ap = *(const s16x8*)&Ps[wid][frow * PLD + ks * 32 + fk];
#pragma unroll
        for (int nt2 = 0; nt2 < 2; nt2++) {
          s16x8 bv = *(const s16x8*)&Vt[(nt2 * 16 + frow) * VLD + ks * 32 + fk];
          oacc[nt2] = __builtin_amdgcn_mfma_f32_16x16x32_bf16(ap, bv, oacc[nt2], 0, 0, 0);
        }
      }
#pragma unroll
      for (int nt2 = 0; nt2 < 2; nt2++)
#pragma unroll
        for (int r = 0; r < 4; r++) {
          int rowg = mt * 16 + quad * 4 + r;
          if (rowg < S_)
            o[(size_t)(b * S_ + rowg) * D_ + h * 32 + nt2 * 16 + frow] = f2b(oacc[nt2][r]);
        }
    }
    __syncthreads();
  }
}

// ---------------------------------------------------------------------------
// x = LN(x + y) * g + b over D=256. One row per 64-lane wave, 4 elems/lane,
// vector loads, pure shuffle reduction (no LDS). 4 rows per 256-thr block.
// ---------------------------------------------------------------------------
__global__ __launch_bounds__(256) void resln_kernel(int yOff,
    const void* g, size_t gOff, const void* bta, size_t btaOff)
{
  const int f = g_f32flag;
  int row = blockIdx.x * 4 + (threadIdx.x >> 6);
  int lane = threadIdx.x & 63;
  u16* xp = g_ws + XOFF + (size_t)row * D_ + lane * 4;
  const u16* yp = g_ws + yOff + (size_t)row * D_ + lane * 4;
  ushort4 xv = *(const ushort4*)xp;
  ushort4 yv = *(const ushort4*)yp;
  float r0 = b2f(xv.x) + b2f(yv.x);
  float r1 = b2f(xv.y) + b2f(yv.y);
  float r2 = b2f(xv.z) + b2f(yv.z);
  float r3 = b2f(xv.w) + b2f(yv.w);
  float s1 = r0 + r1 + r2 + r3;
  float s2 = r0 * r0 + r1 * r1 + r2 * r2 + r3 * r3;
#pragma unroll
  for (int m = 1; m < 64; m <<= 1) {
    s1 += __shfl_xor(s1, m, 64);
    s2 += __shfl_xor(s2, m, 64);
  }
  float mean = s1 * (1.f / 256.f);
  float var = s2 * (1.f / 256.f) - mean * mean;
  float rs = rsqrtf(var + 1e-5f);
  int c0 = lane * 4;
  ushort4 outv;
  outv.x = f2b((r0 - mean) * rs * ldf(g, gOff + c0 + 0, f) + ldf(bta, btaOff + c0 + 0, f));
  outv.y = f2b((r1 - mean) * rs * ldf(g, gOff + c0 + 1, f) + ldf(bta, btaOff + c0 + 1, f));
  outv.z = f2b((r2 - mean) * rs * ldf(g, gOff + c0 + 2, f) + ldf(bta, btaOff + c0 + 2, f));
  outv.w = f2b((r3 - mean) * rs * ldf(g, gOff + c0 + 3, f) + ldf(bta, btaOff + c0 + 3, f));
  *(ushort4*)xp = outv;
}

// ---------------------------------------------------------------------------
// Head: cls row -> two LNs (shared stats) -> two tiny matvecs.
// ---------------------------------------------------------------------------
__global__ __launch_bounds__(256) void head_kernel(
    const void* dg, const void* dbt, const void* dW, const void* dbias,
    const void* ag, const void* abt, const void* aW, const void* abias,
    void* out)
{
  const int f = g_f32flag;
  const u16* x = g_ws + XOFF;
  int bg = blockIdx.x;
  int tid = threadIdx.x;
  float c = b2f(x[(size_t)bg * S_ * D_ + tid]);
  float s1 = c, s2 = c * c;
#pragma unroll
  for (int off = 32; off > 0; off >>= 1) {
    s1 += __shfl_down(s1, off, 64);
    s2 += __shfl_down(s2, off, 64);
  }
  __shared__ float ws1[4], ws2[4], stats[2];
  __shared__ float lnD[256], lnA[256];
  int wid = tid >> 6, lane = tid & 63;
  if (lane == 0) { ws1[wid] = s1; ws2[wid] = s2; }
  __syncthreads();
  if (tid == 0) {
    float t1 = ws1[0] + ws1[1] + ws1[2] + ws1[3];
    float t2 = ws2[0] + ws2[1] + ws2[2] + ws2[3];
    float mean = t1 * (1.f / 256.f);
    float var = t2 * (1.f / 256.f) - mean * mean;
    stats[0] = mean;
    stats[1] = rsqrtf(var + 1e-5f);
  }
  __syncthreads();
  float n = (c - stats[0]) * stats[1];
  lnD[tid] = n * ldf(dg, tid, f) + ldf(dbt, tid, f);
  lnA[tid] = n * ldf(ag, tid, f) + ldf(abt, tid, f);
  __syncthreads();
  if (tid < NC_) {
    float acc = ldf(dbias, tid, f);
    for (int k = 0; k < D_; k++) acc += lnD[k] * ldf(dW, k * NC_ + tid, f);
    if (f) ((float*)out)[bg * NC_ + tid] = acc;
    else   ((bf16*)out)[bg * NC_ + tid] = __float2bfloat16(acc);
  } else if (tid == 8) {
    float acc = ldf(abias, 0, f);
    for (int k = 0; k < D_; k++) acc += lnA[k] * ldf(aW, k, f);
    if (f) ((float*)out)[B_ * NC_ + bg] = acc;
    else   ((bf16*)out)[B_ * NC_ + bg] = __float2bfloat16(acc);
  }
}

// ---------------------------------------------------------------------------
extern "C" void kernel_launch(void* const* d_in, const int* in_sizes, int n_in,
                              void* d_out, int out_size, void* d_ws, size_t ws_size,
                              hipStream_t stream)
{
  (void)in_sizes; (void)out_size; (void)d_ws; (void)ws_size;
  if (n_in < 34) return;
  const int* token_types  = (const int*)d_in[0];
  const int* decision_ids = (const int*)d_in[1];

  probe_kernel<<<1, 256, 0, stream>>>(d_in[12]);   // pos_embed

  wtrans_kernel<<<(DEPTH_ * D_ * 768 + 255) / 256, 256, 0, stream>>>(
      d_in[14], QKVT_OFF, D_, 768, DEPTH_ * D_ * 768);
  wtrans_kernel<<<(DEPTH_ * D_ * D_ + 255) / 256, 256, 0, stream>>>(
      d_in[16], OUTT_OFF, D_, D_, DEPTH_ * D_ * D_);
  wtrans_kernel<<<(DEPTH_ * D_ * FF_ + 255) / 256, 256, 0, stream>>>(
      d_in[22], FFN1T_OFF, D_, FF_, DEPTH_ * D_ * FF_);
  wtrans_kernel<<<(DEPTH_ * FF_ * D_ + 255) / 256, 256, 0, stream>>>(
      d_in[24], FFN2T_OFF, FF_, D_, DEPTH_ * FF_ * D_);

  embed_kernel<<<MTOT, 256, 0, stream>>>(token_types, decision_ids,
      d_in[2], d_in[3], d_in[4], d_in[5], d_in[6], d_in[7], d_in[8],
      d_in[9], d_in[10], d_in[11], d_in[12], d_in[13]);

  for (int i = 0; i < DEPTH_; i++) {
    gemm_mfma<<<dim3(768 / 128, MT128), 256, 0, stream>>>(XOFF,
        QKVT_OFF + i * D_ * 768, d_in[15], (size_t)i * 768, C1OFF, 768, D_, 0);
    attn_kernel<<<B_ * H_, 256, 0, stream>>>();
    gemm_mfma<<<dim3(D_ / 128, MT128), 256, 0, stream>>>(C2OFF,
        OUTT_OFF + i * D_ * D_, d_in[17], (size_t)i * D_, C1OFF, D_, D_, 0);   // y1 -> c1
    resln_kernel<<<MTOT / 4, 256, 0, stream>>>(C1OFF,
        d_in[18], (size_t)i * D_, d_in[19], (size_t)i * D_);
    gemm_mfma<<<dim3(FF_ / 128, MT128), 256, 0, stream>>>(XOFF,
        FFN1T_OFF + i * D_ * FF_, d_in[23], (size_t)i * FF_, C1OFF, FF_, D_, 1);
    gemm_mfma<<<dim3(D_ / 128, MT128), 256, 0, stream>>>(C1OFF,
        FFN2T_OFF + i * FF_ * D_, d_in[25], (size_t)i * D_, C2OFF, D_, FF_, 0); // y2 -> c2
    resln_kernel<<<MTOT / 4, 256, 0, stream>>>(C2OFF,
        d_in[20], (size_t)i * D_, d_in[21], (size_t)i * D_);
  }
  head_kernel<<<B_, 256, 0, stream>>>(d_in[26], d_in[27], d_in[28], d_in[29],
      d_in[30], d_in[31], d_in[32], d_in[33], d_out);
}

// Round 8
// 3156.121 us; speedup vs baseline: 5.5238x; 1.1265x over previous
//
#include <hip/hip_runtime.h>
#include <hip/hip_bf16.h>

typedef __hip_bfloat16 bf16;
typedef unsigned short u16;
typedef __attribute__((ext_vector_type(8))) short s16x8;   // 8 bf16 (4 VGPRs) MFMA frag
typedef __attribute__((ext_vector_type(4))) float f32x4;   // MFMA accumulator

#define B_ 512
#define T_ 150
#define S_ 151
#define D_ 256
#define H_ 8
#define HD_ 32
#define FF_ 1024
#define NC_ 4
#define DEPTH_ 6
#define MTOT 77312            // B_*S_ = 128 * 604
#define MT128 (MTOT / 128)    // 604

// bf16 workspace regions (elements):
#define XOFF 0
#define C1OFF (MTOT * D_)               // x: MTOT*256
#define C2OFF (C1OFF + MTOT * FF_)      // c1: MTOT*1024 (qkv / ffn / y reuse)
#define WSELEMS (C2OFF + MTOT * D_)     // c2: MTOT*256

// Transposed bf16 weights Wt[N][K], all layers, rebuilt per call:
#define QKVT_OFF 0
#define OUTT_OFF (QKVT_OFF + DEPTH_ * D_ * 768)
#define FFN1T_OFF (OUTT_OFF + DEPTH_ * D_ * D_)
#define FFN2T_OFF (FFN1T_OFF + DEPTH_ * D_ * FF_)
#define WTELEMS (FFN2T_OFF + DEPTH_ * FF_ * D_)    // 9.4 MB

// Static device memory (d_ws proved unusable rounds 1-3).
__device__ __align__(16) u16 g_ws[WSELEMS];
__device__ __align__(16) u16 g_wt[WTELEMS];
__device__ int g_f32flag;   // 1 => external buffers f32, 0 => bf16

__device__ __forceinline__ float ldf(const void* p, size_t i, int f) {
  return f ? ((const float*)p)[i] : __bfloat162float(((const bf16*)p)[i]);
}
__device__ __forceinline__ float b2f(u16 u) {
  union { unsigned int i; float f; } v; v.i = ((unsigned int)u) << 16; return v.f;
}
__device__ __forceinline__ u16 f2b(float x) {
  bf16 h = __float2bfloat16(x);
  return *reinterpret_cast<u16*>(&h);
}

// Async global->LDS, 16 B/lane. LDS dest = wave-uniform base + lane*16.
typedef __attribute__((address_space(3))) void lds_void;
typedef const __attribute__((address_space(1))) void glob_void;
__device__ __forceinline__ void gload_lds16(const u16* g, u16* l) {
  __builtin_amdgcn_global_load_lds((glob_void*)g, (lds_void*)l, 16, 0, 0);
}

// ---------------------------------------------------------------------------
// Dtype probe on pos_embed (38656 elems ~N(0,0.02^2)) viewed as 16-bit words.
// ---------------------------------------------------------------------------
#define PROBE_N 38656
__global__ __launch_bounds__(256) void probe_kernel(const void* pe)
{
  const u16* w = (const u16*)pe;
  int susp = 0, zeroEven = 0;
  for (int k = threadIdx.x; k < PROBE_N; k += 256) {
    u16 u = w[k];
    int ex = (u >> 7) & 0xFF;
    if (ex >= 141) susp++;
    if ((k & 1) == 0 && (u & 0x7FFF) == 0) zeroEven++;
  }
  __shared__ int s_susp, s_zero;
  if (threadIdx.x == 0) { s_susp = 0; s_zero = 0; }
  __syncthreads();
  atomicAdd(&s_susp, susp);
  atomicAdd(&s_zero, zeroEven);
  __syncthreads();
  if (threadIdx.x == 0)
    g_f32flag = (s_susp > 0 || s_zero >= ((PROBE_N / 2) * 9) / 10) ? 1 : 0;
}

// ---------------------------------------------------------------------------
// Weight transpose+convert: Wt[l][n][k] = W[l][k][n] as bf16.
// ---------------------------------------------------------------------------
__global__ __launch_bounds__(256) void wtrans_kernel(const void* src, int dstOff,
                                                     int K, int N, int total)
{
  const int f = g_f32flag;
  int idx = blockIdx.x * 256 + threadIdx.x;
  if (idx >= total) return;
  int kn = K * N;
  int l = idx / kn;
  int r = idx - l * kn;
  int k = r / N;
  int n = r - k * N;
  g_wt[dstOff + (size_t)l * kn + (size_t)n * K + k] = f2b(ldf(src, idx, f));
}

// ---------------------------------------------------------------------------
// Embedding: row = blockIdx.x, writes bf16 x.
// ---------------------------------------------------------------------------
__global__ __launch_bounds__(256) void embed_kernel(
    const int* __restrict__ tt, const int* __restrict__ dids,
    const void* av, const void* dv, const void* vv,
    const void* aW, const void* ab, const void* dW, const void* db,
    const void* vW, const void* vb, const void* table, const void* pos,
    const void* cls)
{
  const int f = g_f32flag;
  u16* x = g_ws + XOFF;
  int row = blockIdx.x;
  int d = threadIdx.x;
  int b = row / S_;
  int s = row - b * S_;
  float val;
  if (s == 0) {
    val = ldf(cls, d, f);
  } else {
    int t = s - 1;
    int idx = b * T_ + t;
    int ty = tt[idx];
    if (ty == 0) {
      val = ldf(av, idx, f) * ldf(aW, d, f) + ldf(ab, d, f);
    } else if (ty == 1) {
      float acc = ldf(db, d, f) + ldf(vb, d, f);
#pragma unroll
      for (int i = 0; i < 10; i++) acc += ldf(dv, (size_t)idx * 10 + i, f) * ldf(dW, i * D_ + d, f);
#pragma unroll
      for (int i = 0; i < 3; i++) acc += ldf(vv, (size_t)idx * 3 + i, f) * ldf(vW, i * D_ + d, f);
      val = acc;
    } else if (ty == 2) {
      int did = dids[idx] & (NC_ - 1);
      val = ldf(table, (size_t)did * D_ + d, f);
    } else {
      val = 0.f;
    }
  }
  val += ldf(pos, s * D_ + d, f);
  x[(size_t)row * D_ + d] = f2b(val);
}

// ---------------------------------------------------------------------------
// MFMA GEMM: C[M,N] = A[M,K] @ W[K,N] + bias (opt relu). Bt[N][K] in g_wt.
// 128x128 tile, BK=32, 4 waves x 64x64 quadrant. Staging via
// global_load_lds width=16 (m97 ladder): per kt, each wave issues 2 A-row
// groups + 2 B-row groups of 16 rows x 64 B. M = 604*128 exactly.
// ---------------------------------------------------------------------------
__global__ __launch_bounds__(256) void gemm_mfma(
    int aOff, int wtOff, const void* bias, size_t bOff,
    int cOff, int N, int K, int relu)
{
  const int f = g_f32flag;
  const u16* A = g_ws + aOff;
  const u16* Bt = g_wt + wtOff;
  u16* C = g_ws + cOff;
  __shared__ __align__(16) u16 As[128 * 32];
  __shared__ __align__(16) u16 Bs[128 * 32];
  const int tid = threadIdx.x;
  const int bm = blockIdx.y, bn = blockIdx.x;
  const int lane = tid & 63, wid = tid >> 6;
  const int wm = (wid >> 1) * 64, wn = (wid & 1) * 64;
  const int frow = lane & 15, fk = (lane >> 4) * 8;

  // Staging addresses: group g = wid*2+p covers rows g*16 + (lane>>2),
  // u16 col (lane&3)*8. LDS byte offset = lane*16 within group's 1 KiB.
  const int sr = lane >> 2;
  const int sc = (lane & 3) * 8;
  const int r0 = (wid * 2 + 0) * 16 + sr;
  const int r1 = (wid * 2 + 1) * 16 + sr;
  const u16* Ag0 = A + (size_t)(bm * 128 + r0) * K + sc;
  const u16* Ag1 = A + (size_t)(bm * 128 + r1) * K + sc;
  const u16* Bg0 = Bt + (size_t)(bn * 128 + r0) * K + sc;
  const u16* Bg1 = Bt + (size_t)(bn * 128 + r1) * K + sc;
  u16* Asl0 = &As[(wid * 2 + 0) * 512];
  u16* Asl1 = &As[(wid * 2 + 1) * 512];
  u16* Bsl0 = &Bs[(wid * 2 + 0) * 512];
  u16* Bsl1 = &Bs[(wid * 2 + 1) * 512];

  f32x4 acc[4][4] = {};

  for (int kt = 0; kt < K; kt += 32) {
    if (kt) __syncthreads();
    gload_lds16(Ag0 + kt, Asl0);
    gload_lds16(Ag1 + kt, Asl1);
    gload_lds16(Bg0 + kt, Bsl0);
    gload_lds16(Bg1 + kt, Bsl1);
    __syncthreads();   // drains vmcnt(0): LDS data landed
    s16x8 af[4], bfr[4];
#pragma unroll
    for (int t = 0; t < 4; t++) {
      af[t]  = *(const s16x8*)&As[(wm + t * 16 + frow) * 32 + fk];
      bfr[t] = *(const s16x8*)&Bs[(wn + t * 16 + frow) * 32 + fk];
    }
#pragma unroll
    for (int mt = 0; mt < 4; mt++)
#pragma unroll
      for (int nt = 0; nt < 4; nt++)
        acc[mt][nt] = __builtin_amdgcn_mfma_f32_16x16x32_bf16(af[mt], bfr[nt], acc[mt][nt], 0, 0, 0);
  }

  const int ccol = lane & 15;
  const int crow0 = (lane >> 4) * 4;
  float bv[4];
#pragma unroll
  for (int nt = 0; nt < 4; nt++)
    bv[nt] = ldf(bias, bOff + (size_t)(bn * 128 + wn + nt * 16 + ccol), f);
#pragma unroll
  for (int mt = 0; mt < 4; mt++) {
#pragma unroll
    for (int nt = 0; nt < 4; nt++) {
      int colg = bn * 128 + wn + nt * 16 + ccol;
#pragma unroll
      for (int r = 0; r < 4; r++) {
        int rowg = bm * 128 + wm + mt * 16 + crow0 + r;
        float v = acc[mt][nt][r] + bv[nt];
        if (relu) v = fmaxf(v, 0.f);
        C[(size_t)rowg * N + colg] = f2b(v);
      }
    }
  }
}

// ---------------------------------------------------------------------------
// MFMA attention (S=151 padded 160). One block per (b,h), 320 thr = 5 waves,
// each wave 2 m-tiles (mt = round*5+wid), fully independent after staging:
// Ps is wave-private, so NO barriers in the round loop (same-wave ds
// ordering enforced by compiler lgkmcnt). Softmax normalization deferred to
// the O epilogue. K/V staged with 16-B vector loads (V transposed on write).
// ---------------------------------------------------------------------------
#define SP 160
#define KLD 40
#define VLD 168
#define PLD 168

__global__ __launch_bounds__(320) void attn_kernel()
{
  const u16* qkv = g_ws + C1OFF;
  u16* o = g_ws + C2OFF;
  __shared__ __align__(16) u16 Ks[SP * KLD];        // [j][d]  12800 B
  __shared__ __align__(16) u16 Vt[HD_ * VLD];       // [d][j]  10752 B
  __shared__ __align__(16) u16 Ps[5][16 * PLD];     // wave-private P tiles
  int bh = blockIdx.x;
  int b = bh >> 3, h = bh & 7;
  int tid = threadIdx.x;
  int lane = tid & 63, wid = tid >> 6;
  const u16* base = qkv + (size_t)b * S_ * 768;

  // Stage K: 16-B vector load per (row, 8-col group). SP*4 = 640 groups.
  for (int g = tid; g < SP * 4; g += 320) {
    int j = g >> 2, d0 = (g & 3) * 8;
    s16x8 kv = {0, 0, 0, 0, 0, 0, 0, 0};
    if (j < S_) kv = *(const s16x8*)(base + (size_t)j * 768 + 256 + h * 32 + d0);
    *(s16x8*)&Ks[j * KLD + d0] = kv;
  }
  // Stage V transposed: vector global read, 8 scalar LDS writes.
  for (int g = tid; g < SP * 4; g += 320) {
    int j = g >> 2, d0 = (g & 3) * 8;
    s16x8 vv = {0, 0, 0, 0, 0, 0, 0, 0};
    if (j < S_) vv = *(const s16x8*)(base + (size_t)j * 768 + 512 + h * 32 + d0);
#pragma unroll
    for (int i = 0; i < 8; i++) Vt[(d0 + i) * VLD + j] = (u16)vv[i];
  }
  __syncthreads();

  const int frow = lane & 15;
  const int quad = lane >> 4;
  const int fk = quad * 8;
  const float scale = 0.17677669529663687f;  // 1/sqrt(32)

  for (int round = 0; round < 2; round++) {
    int mt = round * 5 + wid;
    // Q A-frag straight from global.
    int qrow = mt * 16 + frow;
    s16x8 aq = {0, 0, 0, 0, 0, 0, 0, 0};
    if (qrow < S_) aq = *(const s16x8*)(base + (size_t)qrow * 768 + h * 32 + fk);
    f32x4 sacc[10];
#pragma unroll
    for (int nt = 0; nt < 10; nt++) {
      s16x8 bk = *(const s16x8*)&Ks[(nt * 16 + frow) * KLD + fk];
      f32x4 z = {0.f, 0.f, 0.f, 0.f};
      sacc[nt] = __builtin_amdgcn_mfma_f32_16x16x32_bf16(aq, bk, z, 0, 0, 0);
    }
    // Scale + mask cols >= S_ (C-layout: col = frow within n-tile).
#pragma unroll
    for (int nt = 0; nt < 10; nt++) {
      int colg = nt * 16 + frow;
      float msk = (colg < S_) ? 1.f : 0.f;
#pragma unroll
      for (int r = 0; r < 4; r++)
        sacc[nt][r] = msk ? sacc[nt][r] * scale : -1e30f;
    }
    // Row softmax (rows = quad*4+r live across the quad's 16 lanes).
    float inv[4];
#pragma unroll
    for (int r = 0; r < 4; r++) {
      float mx = -1e30f;
#pragma unroll
      for (int nt = 0; nt < 10; nt++) mx = fmaxf(mx, sacc[nt][r]);
#pragma unroll
      for (int m = 1; m < 16; m <<= 1) mx = fmaxf(mx, __shfl_xor(mx, m, 64));
      float sm = 0.f;
#pragma unroll
      for (int nt = 0; nt < 10; nt++) {
        float p = __expf(sacc[nt][r] - mx);
        sacc[nt][r] = p;
        sm += p;
      }
#pragma unroll
      for (int m = 1; m < 16; m <<= 1) sm += __shfl_xor(sm, m, 64);
      inv[r] = 1.f / sm;
    }
    // C-layout -> A-layout via wave-private LDS (unnormalized P).
#pragma unroll
    for (int nt = 0; nt < 10; nt++)
#pragma unroll
      for (int r = 0; r < 4; r++)
        Ps[wid][(quad * 4 + r) * PLD + nt * 16 + frow] = f2b(sacc[nt][r]);
    // P @ V (same-wave LDS dependency; compiler inserts lgkmcnt waits).
    f32x4 oacc[2] = {};
#pragma unroll
    for (int ks = 0; ks < 5; ks++) {
      s16x8 ap = *(const s16x8*)&Ps[wid][frow * PLD + ks * 32 + fk];
#pragma unroll
      for (int nt2 = 0; nt2 < 2; nt2++) {
        s16x8 bv = *(const s16x8*)&Vt[(nt2 * 16 + frow) * VLD + ks * 32 + fk];
        oacc[nt2] = __builtin_amdgcn_mfma_f32_16x16x32_bf16(ap, bv, oacc[nt2], 0, 0, 0);
      }
    }
#pragma unroll
    for (int nt2 = 0; nt2 < 2; nt2++)
#pragma unroll
      for (int r = 0; r < 4; r++) {
        int rowg = mt * 16 + quad * 4 + r;
        if (rowg < S_)
          o[(size_t)(b * S_ + rowg) * D_ + h * 32 + nt2 * 16 + frow] = f2b(oacc[nt2][r] * inv[r]);
      }
  }
}

// ---------------------------------------------------------------------------
// x = LN(x + y) * g + b over D=256. One row per wave, ushort4 loads,
// pure shuffle reduction. 4 rows per 256-thr block.
// ---------------------------------------------------------------------------
__global__ __launch_bounds__(256) void resln_kernel(int yOff,
    const void* g, size_t gOff, const void* bta, size_t btaOff)
{
  const int f = g_f32flag;
  int row = blockIdx.x * 4 + (threadIdx.x >> 6);
  int lane = threadIdx.x & 63;
  u16* xp = g_ws + XOFF + (size_t)row * D_ + lane * 4;
  const u16* yp = g_ws + yOff + (size_t)row * D_ + lane * 4;
  ushort4 xv = *(const ushort4*)xp;
  ushort4 yv = *(const ushort4*)yp;
  float r0 = b2f(xv.x) + b2f(yv.x);
  float r1 = b2f(xv.y) + b2f(yv.y);
  float r2 = b2f(xv.z) + b2f(yv.z);
  float r3 = b2f(xv.w) + b2f(yv.w);
  float s1 = r0 + r1 + r2 + r3;
  float s2 = r0 * r0 + r1 * r1 + r2 * r2 + r3 * r3;
#pragma unroll
  for (int m = 1; m < 64; m <<= 1) {
    s1 += __shfl_xor(s1, m, 64);
    s2 += __shfl_xor(s2, m, 64);
  }
  float mean = s1 * (1.f / 256.f);
  float var = s2 * (1.f / 256.f) - mean * mean;
  float rs = rsqrtf(var + 1e-5f);
  int c0 = lane * 4;
  ushort4 outv;
  outv.x = f2b((r0 - mean) * rs * ldf(g, gOff + c0 + 0, f) + ldf(bta, btaOff + c0 + 0, f));
  outv.y = f2b((r1 - mean) * rs * ldf(g, gOff + c0 + 1, f) + ldf(bta, btaOff + c0 + 1, f));
  outv.z = f2b((r2 - mean) * rs * ldf(g, gOff + c0 + 2, f) + ldf(bta, btaOff + c0 + 2, f));
  outv.w = f2b((r3 - mean) * rs * ldf(g, gOff + c0 + 3, f) + ldf(bta, btaOff + c0 + 3, f));
  *(ushort4*)xp = outv;
}

// ---------------------------------------------------------------------------
// Head: cls row -> two LNs (shared stats) -> two tiny matvecs.
// ---------------------------------------------------------------------------
__global__ __launch_bounds__(256) void head_kernel(
    const void* dg, const void* dbt, const void* dW, const void* dbias,
    const void* ag, const void* abt, const void* aW, const void* abias,
    void* out)
{
  const int f = g_f32flag;
  const u16* x = g_ws + XOFF;
  int bg = blockIdx.x;
  int tid = threadIdx.x;
  float c = b2f(x[(size_t)bg * S_ * D_ + tid]);
  float s1 = c, s2 = c * c;
#pragma unroll
  for (int off = 32; off > 0; off >>= 1) {
    s1 += __shfl_down(s1, off, 64);
    s2 += __shfl_down(s2, off, 64);
  }
  __shared__ float ws1[4], ws2[4], stats[2];
  __shared__ float lnD[256], lnA[256];
  int wid = tid >> 6, lane = tid & 63;
  if (lane == 0) { ws1[wid] = s1; ws2[wid] = s2; }
  __syncthreads();
  if (tid == 0) {
    float t1 = ws1[0] + ws1[1] + ws1[2] + ws1[3];
    float t2 = ws2[0] + ws2[1] + ws2[2] + ws2[3];
    float mean = t1 * (1.f / 256.f);
    float var = t2 * (1.f / 256.f) - mean * mean;
    stats[0] = mean;
    stats[1] = rsqrtf(var + 1e-5f);
  }
  __syncthreads();
  float n = (c - stats[0]) * stats[1];
  lnD[tid] = n * ldf(dg, tid, f) + ldf(dbt, tid, f);
  lnA[tid] = n * ldf(ag, tid, f) + ldf(abt, tid, f);
  __syncthreads();
  if (tid < NC_) {
    float acc = ldf(dbias, tid, f);
    for (int k = 0; k < D_; k++) acc += lnD[k] * ldf(dW, k * NC_ + tid, f);
    if (f) ((float*)out)[bg * NC_ + tid] = acc;
    else   ((bf16*)out)[bg * NC_ + tid] = __float2bfloat16(acc);
  } else if (tid == 8) {
    float acc = ldf(abias, 0, f);
    for (int k = 0; k < D_; k++) acc += lnA[k] * ldf(aW, k, f);
    if (f) ((float*)out)[B_ * NC_ + bg] = acc;
    else   ((bf16*)out)[B_ * NC_ + bg] = __float2bfloat16(acc);
  }
}

// ---------------------------------------------------------------------------
extern "C" void kernel_launch(void* const* d_in, const int* in_sizes, int n_in,
                              void* d_out, int out_size, void* d_ws, size_t ws_size,
                              hipStream_t stream)
{
  (void)in_sizes; (void)out_size; (void)d_ws; (void)ws_size;
  if (n_in < 34) return;
  const int* token_types  = (const int*)d_in[0];
  const int* decision_ids = (const int*)d_in[1];

  probe_kernel<<<1, 256, 0, stream>>>(d_in[12]);   // pos_embed

  wtrans_kernel<<<(DEPTH_ * D_ * 768 + 255) / 256, 256, 0, stream>>>(
      d_in[14], QKVT_OFF, D_, 768, DEPTH_ * D_ * 768);
  wtrans_kernel<<<(DEPTH_ * D_ * D_ + 255) / 256, 256, 0, stream>>>(
      d_in[16], OUTT_OFF, D_, D_, DEPTH_ * D_ * D_);
  wtrans_kernel<<<(DEPTH_ * D_ * FF_ + 255) / 256, 256, 0, stream>>>(
      d_in[22], FFN1T_OFF, D_, FF_, DEPTH_ * D_ * FF_);
  wtrans_kernel<<<(DEPTH_ * FF_ * D_ + 255) / 256, 256, 0, stream>>>(
      d_in[24], FFN2T_OFF, FF_, D_, DEPTH_ * FF_ * D_);

  embed_kernel<<<MTOT, 256, 0, stream>>>(token_types, decision_ids,
      d_in[2], d_in[3], d_in[4], d_in[5], d_in[6], d_in[7], d_in[8],
      d_in[9], d_in[10], d_in[11], d_in[12], d_in[13]);

  for (int i = 0; i < DEPTH_; i++) {
    gemm_mfma<<<dim3(768 / 128, MT128), 256, 0, stream>>>(XOFF,
        QKVT_OFF + i * D_ * 768, d_in[15], (size_t)i * 768, C1OFF, 768, D_, 0);
    attn_kernel<<<B_ * H_, 320, 0, stream>>>();
    gemm_mfma<<<dim3(D_ / 128, MT128), 256, 0, stream>>>(C2OFF,
        OUTT_OFF + i * D_ * D_, d_in[17], (size_t)i * D_, C1OFF, D_, D_, 0);   // y1 -> c1
    resln_kernel<<<MTOT / 4, 256, 0, stream>>>(C1OFF,
        d_in[18], (size_t)i * D_, d_in[19], (size_t)i * D_);
    gemm_mfma<<<dim3(FF_ / 128, MT128), 256, 0, stream>>>(XOFF,
        FFN1T_OFF + i * D_ * FF_, d_in[23], (size_t)i * FF_, C1OFF, FF_, D_, 1);
    gemm_mfma<<<dim3(D_ / 128, MT128), 256, 0, stream>>>(C1OFF,
        FFN2T_OFF + i * FF_ * D_, d_in[25], (size_t)i * D_, C2OFF, D_, FF_, 0); // y2 -> c2
    resln_kernel<<<MTOT / 4, 256, 0, stream>>>(C2OFF,
        d_in[20], (size_t)i * D_, d_in[21], (size_t)i * D_);
  }
  head_kernel<<<B_, 256, 0, stream>>>(d_in[26], d_in[27], d_in[28], d_in[29],
      d_in[30], d_in[31], d_in[32], d_in[33], d_out);
}

// Round 9
// 3111.039 us; speedup vs baseline: 5.6039x; 1.0145x over previous
//
#include <hip/hip_runtime.h>
#include <hip/hip_bf16.h>

typedef __hip_bfloat16 bf16;
typedef unsigned short u16;
typedef __attribute__((ext_vector_type(8))) short s16x8;   // 8 bf16 (4 VGPRs) MFMA frag
typedef __attribute__((ext_vector_type(4))) float f32x4;   // MFMA accumulator

#define B_ 512
#define T_ 150
#define S_ 151
#define D_ 256
#define H_ 8
#define HD_ 32
#define FF_ 1024
#define NC_ 4
#define DEPTH_ 6
#define MTOT 77312            // B_*S_ = 128 * 604
#define MT128 (MTOT / 128)    // 604

// bf16 workspace regions (elements):
#define XOFF 0
#define C1OFF (MTOT * D_)               // x: MTOT*256
#define C2OFF (C1OFF + MTOT * FF_)      // c1: MTOT*1024 (qkv / ffn / y reuse)
#define WSELEMS (C2OFF + MTOT * D_)     // c2: MTOT*256

// Transposed bf16 weights Wt[N][K], all layers, rebuilt per call:
#define QKVT_OFF 0
#define OUTT_OFF (QKVT_OFF + DEPTH_ * D_ * 768)
#define FFN1T_OFF (OUTT_OFF + DEPTH_ * D_ * D_)
#define FFN2T_OFF (FFN1T_OFF + DEPTH_ * D_ * FF_)
#define WTELEMS (FFN2T_OFF + DEPTH_ * FF_ * D_)    // 9.4 MB

// Static device memory (d_ws proved unusable rounds 1-3).
__device__ __align__(16) u16 g_ws[WSELEMS];
__device__ __align__(16) u16 g_wt[WTELEMS];
__device__ int g_f32flag;   // 1 => external buffers f32, 0 => bf16

__device__ __forceinline__ float ldf(const void* p, size_t i, int f) {
  return f ? ((const float*)p)[i] : __bfloat162float(((const bf16*)p)[i]);
}
__device__ __forceinline__ float b2f(u16 u) {
  union { unsigned int i; float f; } v; v.i = ((unsigned int)u) << 16; return v.f;
}
__device__ __forceinline__ u16 f2b(float x) {
  bf16 h = __float2bfloat16(x);
  return *reinterpret_cast<u16*>(&h);
}

// Async global->LDS, 16 B/lane. LDS dest = wave-uniform base + lane*16.
typedef __attribute__((address_space(3))) void lds_void;
typedef const __attribute__((address_space(1))) void glob_void;
__device__ __forceinline__ void gload_lds16(const u16* g, u16* l) {
  __builtin_amdgcn_global_load_lds((glob_void*)g, (lds_void*)l, 16, 0, 0);
}

// ---------------------------------------------------------------------------
// Dtype probe on pos_embed (38656 elems ~N(0,0.02^2)) viewed as 16-bit words.
// ---------------------------------------------------------------------------
#define PROBE_N 38656
__global__ __launch_bounds__(256) void probe_kernel(const void* pe)
{
  const u16* w = (const u16*)pe;
  int susp = 0, zeroEven = 0;
  for (int k = threadIdx.x; k < PROBE_N; k += 256) {
    u16 u = w[k];
    int ex = (u >> 7) & 0xFF;
    if (ex >= 141) susp++;
    if ((k & 1) == 0 && (u & 0x7FFF) == 0) zeroEven++;
  }
  __shared__ int s_susp, s_zero;
  if (threadIdx.x == 0) { s_susp = 0; s_zero = 0; }
  __syncthreads();
  atomicAdd(&s_susp, susp);
  atomicAdd(&s_zero, zeroEven);
  __syncthreads();
  if (threadIdx.x == 0)
    g_f32flag = (s_susp > 0 || s_zero >= ((PROBE_N / 2) * 9) / 10) ? 1 : 0;
}

// ---------------------------------------------------------------------------
// Weight transpose+convert: Wt[l][n][k] = W[l][k][n] as bf16.
// ---------------------------------------------------------------------------
__global__ __launch_bounds__(256) void wtrans_kernel(const void* src, int dstOff,
                                                     int K, int N, int total)
{
  const int f = g_f32flag;
  int idx = blockIdx.x * 256 + threadIdx.x;
  if (idx >= total) return;
  int kn = K * N;
  int l = idx / kn;
  int r = idx - l * kn;
  int k = r / N;
  int n = r - k * N;
  g_wt[dstOff + (size_t)l * kn + (size_t)n * K + k] = f2b(ldf(src, idx, f));
}

// ---------------------------------------------------------------------------
// Embedding: row = blockIdx.x, writes bf16 x.
// ---------------------------------------------------------------------------
__global__ __launch_bounds__(256) void embed_kernel(
    const int* __restrict__ tt, const int* __restrict__ dids,
    const void* av, const void* dv, const void* vv,
    const void* aW, const void* ab, const void* dW, const void* db,
    const void* vW, const void* vb, const void* table, const void* pos,
    const void* cls)
{
  const int f = g_f32flag;
  u16* x = g_ws + XOFF;
  int row = blockIdx.x;
  int d = threadIdx.x;
  int b = row / S_;
  int s = row - b * S_;
  float val;
  if (s == 0) {
    val = ldf(cls, d, f);
  } else {
    int t = s - 1;
    int idx = b * T_ + t;
    int ty = tt[idx];
    if (ty == 0) {
      val = ldf(av, idx, f) * ldf(aW, d, f) + ldf(ab, d, f);
    } else if (ty == 1) {
      float acc = ldf(db, d, f) + ldf(vb, d, f);
#pragma unroll
      for (int i = 0; i < 10; i++) acc += ldf(dv, (size_t)idx * 10 + i, f) * ldf(dW, i * D_ + d, f);
#pragma unroll
      for (int i = 0; i < 3; i++) acc += ldf(vv, (size_t)idx * 3 + i, f) * ldf(vW, i * D_ + d, f);
      val = acc;
    } else if (ty == 2) {
      int did = dids[idx] & (NC_ - 1);
      val = ldf(table, (size_t)did * D_ + d, f);
    } else {
      val = 0.f;
    }
  }
  val += ldf(pos, s * D_ + d, f);
  x[(size_t)row * D_ + d] = f2b(val);
}

// ---------------------------------------------------------------------------
// MFMA GEMM: C[M,N] = A[M,K] @ W[K,N] + bias (opt relu). Bt[N][K] in g_wt.
// 128x128 tile, BK=64, 4 waves x 64x64 quadrant. 1-D grid with XCD-aware
// swizzle (block%8 == XCD gets a fixed bm -> its L2 reuses the A slice).
// Staging: global_load_lds width=16, k-chunks XOR-swizzled by row so the
// fragment ds_read_b128s spread across all 32 banks (conflict-free, since
// padding is impossible with global_load_lds's lane*16 LDS mapping).
// Epilogue: acc -> padded LDS tile (stride 136 u16) -> 16-B vector stores.
// M = 604*128 exactly; N in {256,768,1024}; K in {256,1024}.
// ---------------------------------------------------------------------------
__global__ __launch_bounds__(256) void gemm_mfma(
    int aOff, int wtOff, const void* bias, size_t bOff,
    int cOff, int N, int K, int relu, int NB)
{
  const int f = g_f32flag;
  const u16* A = g_ws + aOff;
  const u16* Bt = g_wt + wtOff;
  u16* C = g_ws + cOff;
  __shared__ __align__(16) u16 sm[16384];   // As = sm[0..8192), Bs = sm[8192..)
  const int tid = threadIdx.x;

  // XCD swizzle: full groups of 8 bm-rows x NB cols; tail linear.
  int gblk = blockIdx.x;
  int bm, bn;
  {
    const int full = (MT128 / 8) * 8;        // 600
    if (gblk < NB * full) {
      int per = NB * 8;
      int grp = gblk / per, rem = gblk % per;
      bm = grp * 8 + (rem & 7);
      bn = rem >> 3;
    } else {
      int id = gblk - NB * full;
      bm = full + id / NB;
      bn = id % NB;
    }
  }

  const int lane = tid & 63, wid = tid >> 6;
  const int wm = (wid >> 1) * 64, wn = (wid & 1) * 64;
  const int frow = lane & 15, quad = lane >> 4;

  // Staging: wave wid stages row-groups wid*4+p (8 rows x 128 B each) for A
  // and B. Lane l: row_in_group = l>>3, global k-chunk = (l&7)^(l>>3)
  // (xor-swizzle; LDS chunk slot is fixed at l&7 by the lane*16 mapping).
  const int rg = lane >> 3;
  const int ck = ((lane & 7) ^ rg) * 8;
  const u16* Ag[4]; const u16* Bg[4];
  u16 *Asl[4], *Bsl[4];
#pragma unroll
  for (int p = 0; p < 4; p++) {
    int grp = wid * 4 + p;                   // 0..15
    int row = grp * 8 + rg;
    Ag[p] = A + (size_t)(bm * 128 + row) * K + ck;
    Bg[p] = Bt + (size_t)(bn * 128 + row) * K + ck;
    Asl[p] = &sm[grp * 512];
    Bsl[p] = &sm[8192 + grp * 512];
  }

  f32x4 acc[4][4] = {};

  for (int kt = 0; kt < K; kt += 64) {
    if (kt) __syncthreads();
#pragma unroll
    for (int p = 0; p < 4; p++) {
      gload_lds16(Ag[p] + kt, Asl[p]);
      gload_lds16(Bg[p] + kt, Bsl[p]);
    }
    __syncthreads();   // drains vmcnt(0): LDS data landed
#pragma unroll
    for (int s = 0; s < 2; s++) {
      s16x8 af[4], bfr[4];
      const int cfr = ((s * 4 + quad) ^ (frow & 7)) * 8;   // un-swizzled chunk
#pragma unroll
      for (int t = 0; t < 4; t++) {
        af[t]  = *(const s16x8*)&sm[(wm + t * 16 + frow) * 64 + cfr];
        bfr[t] = *(const s16x8*)&sm[8192 + (wn + t * 16 + frow) * 64 + cfr];
      }
#pragma unroll
      for (int mt = 0; mt < 4; mt++)
#pragma unroll
        for (int nt = 0; nt < 4; nt++)
          acc[mt][nt] = __builtin_amdgcn_mfma_f32_16x16x32_bf16(af[mt], bfr[nt], acc[mt][nt], 0, 0, 0);
    }
  }

  // Epilogue: C-layout (col = frow, row = quad*4+r) -> LDS 64x136 tile ->
  // coalesced dwordx4 stores. Two 64-row passes (waves 0,1 then 2,3).
  float bv[4];
#pragma unroll
  for (int nt = 0; nt < 4; nt++)
    bv[nt] = ldf(bias, bOff + (size_t)(bn * 128 + wn + nt * 16 + frow), f);
  __syncthreads();   // all frag reads done; sm reusable
#pragma unroll
  for (int p = 0; p < 2; p++) {
    if ((wid >> 1) == p) {
#pragma unroll
      for (int mt = 0; mt < 4; mt++)
#pragma unroll
        for (int nt = 0; nt < 4; nt++)
#pragma unroll
          for (int r = 0; r < 4; r++) {
            int rl = (wm & 63) + mt * 16 + quad * 4 + r;
            float v = acc[mt][nt][r] + bv[nt];
            if (relu) v = fmaxf(v, 0.f);
            sm[rl * 136 + wn + nt * 16 + frow] = f2b(v);
          }
    }
    __syncthreads();
    {
      int rl = tid >> 2;
      int cq = (tid & 3) * 32;
      size_t gb = (size_t)(bm * 128 + p * 64 + rl) * N + bn * 128 + cq;
#pragma unroll
      for (int j = 0; j < 4; j++)
        *(s16x8*)(C + gb + j * 8) = *(const s16x8*)&sm[rl * 136 + cq + j * 8];
    }
    __syncthreads();
  }
}

// ---------------------------------------------------------------------------
// MFMA attention (S=151 padded 160). One block per (b,h), 320 thr = 5 waves,
// each wave 2 m-tiles, no barriers after staging (Ps wave-private).
// ---------------------------------------------------------------------------
#define SP 160
#define KLD 40
#define VLD 168
#define PLD 168

__global__ __launch_bounds__(320) void attn_kernel()
{
  const u16* qkv = g_ws + C1OFF;
  u16* o = g_ws + C2OFF;
  __shared__ __align__(16) u16 Ks[SP * KLD];
  __shared__ __align__(16) u16 Vt[HD_ * VLD];
  __shared__ __align__(16) u16 Ps[5][16 * PLD];
  int bh = blockIdx.x;
  int b = bh >> 3, h = bh & 7;
  int tid = threadIdx.x;
  int lane = tid & 63, wid = tid >> 6;
  const u16* base = qkv + (size_t)b * S_ * 768;

  for (int g = tid; g < SP * 4; g += 320) {
    int j = g >> 2, d0 = (g & 3) * 8;
    s16x8 kv = {0, 0, 0, 0, 0, 0, 0, 0};
    if (j < S_) kv = *(const s16x8*)(base + (size_t)j * 768 + 256 + h * 32 + d0);
    *(s16x8*)&Ks[j * KLD + d0] = kv;
  }
  for (int g = tid; g < SP * 4; g += 320) {
    int j = g >> 2, d0 = (g & 3) * 8;
    s16x8 vv = {0, 0, 0, 0, 0, 0, 0, 0};
    if (j < S_) vv = *(const s16x8*)(base + (size_t)j * 768 + 512 + h * 32 + d0);
#pragma unroll
    for (int i = 0; i < 8; i++) Vt[(d0 + i) * VLD + j] = (u16)vv[i];
  }
  __syncthreads();

  const int frow = lane & 15;
  const int quad = lane >> 4;
  const int fk = quad * 8;
  const float scale = 0.17677669529663687f;  // 1/sqrt(32)

  for (int round = 0; round < 2; round++) {
    int mt = round * 5 + wid;
    int qrow = mt * 16 + frow;
    s16x8 aq = {0, 0, 0, 0, 0, 0, 0, 0};
    if (qrow < S_) aq = *(const s16x8*)(base + (size_t)qrow * 768 + h * 32 + fk);
    f32x4 sacc[10];
#pragma unroll
    for (int nt = 0; nt < 10; nt++) {
      s16x8 bk = *(const s16x8*)&Ks[(nt * 16 + frow) * KLD + fk];
      f32x4 z = {0.f, 0.f, 0.f, 0.f};
      sacc[nt] = __builtin_amdgcn_mfma_f32_16x16x32_bf16(aq, bk, z, 0, 0, 0);
    }
#pragma unroll
    for (int nt = 0; nt < 10; nt++) {
      int colg = nt * 16 + frow;
      float msk = (colg < S_) ? 1.f : 0.f;
#pragma unroll
      for (int r = 0; r < 4; r++)
        sacc[nt][r] = msk ? sacc[nt][r] * scale : -1e30f;
    }
    float inv[4];
#pragma unroll
    for (int r = 0; r < 4; r++) {
      float mx = -1e30f;
#pragma unroll
      for (int nt = 0; nt < 10; nt++) mx = fmaxf(mx, sacc[nt][r]);
#pragma unroll
      for (int m = 1; m < 16; m <<= 1) mx = fmaxf(mx, __shfl_xor(mx, m, 64));
      float sm2 = 0.f;
#pragma unroll
      for (int nt = 0; nt < 10; nt++) {
        float p = __expf(sacc[nt][r] - mx);
        sacc[nt][r] = p;
        sm2 += p;
      }
#pragma unroll
      for (int m = 1; m < 16; m <<= 1) sm2 += __shfl_xor(sm2, m, 64);
      inv[r] = 1.f / sm2;
    }
#pragma unroll
    for (int nt = 0; nt < 10; nt++)
#pragma unroll
      for (int r = 0; r < 4; r++)
        Ps[wid][(quad * 4 + r) * PLD + nt * 16 + frow] = f2b(sacc[nt][r]);
    f32x4 oacc[2] = {};
#pragma unroll
    for (int ks = 0; ks < 5; ks++) {
      s16x8 ap = *(const s16x8*)&Ps[wid][frow * PLD + ks * 32 + fk];
#pragma unroll
      for (int nt2 = 0; nt2 < 2; nt2++) {
        s16x8 bv = *(const s16x8*)&Vt[(nt2 * 16 + frow) * VLD + ks * 32 + fk];
        oacc[nt2] = __builtin_amdgcn_mfma_f32_16x16x32_bf16(ap, bv, oacc[nt2], 0, 0, 0);
      }
    }
#pragma unroll
    for (int nt2 = 0; nt2 < 2; nt2++)
#pragma unroll
      for (int r = 0; r < 4; r++) {
        int rowg = mt * 16 + quad * 4 + r;
        if (rowg < S_)
          o[(size_t)(b * S_ + rowg) * D_ + h * 32 + nt2 * 16 + frow] = f2b(oacc[nt2][r] * inv[r]);
      }
  }
}

// ---------------------------------------------------------------------------
// x = LN(x + y) * g + b over D=256. One row per wave, ushort4 loads,
// pure shuffle reduction. 4 rows per 256-thr block.
// ---------------------------------------------------------------------------
__global__ __launch_bounds__(256) void resln_kernel(int yOff,
    const void* g, size_t gOff, const void* bta, size_t btaOff)
{
  const int f = g_f32flag;
  int row = blockIdx.x * 4 + (threadIdx.x >> 6);
  int lane = threadIdx.x & 63;
  u16* xp = g_ws + XOFF + (size_t)row * D_ + lane * 4;
  const u16* yp = g_ws + yOff + (size_t)row * D_ + lane * 4;
  ushort4 xv = *(const ushort4*)xp;
  ushort4 yv = *(const ushort4*)yp;
  float r0 = b2f(xv.x) + b2f(yv.x);
  float r1 = b2f(xv.y) + b2f(yv.y);
  float r2 = b2f(xv.z) + b2f(yv.z);
  float r3 = b2f(xv.w) + b2f(yv.w);
  float s1 = r0 + r1 + r2 + r3;
  float s2 = r0 * r0 + r1 * r1 + r2 * r2 + r3 * r3;
#pragma unroll
  for (int m = 1; m < 64; m <<= 1) {
    s1 += __shfl_xor(s1, m, 64);
    s2 += __shfl_xor(s2, m, 64);
  }
  float mean = s1 * (1.f / 256.f);
  float var = s2 * (1.f / 256.f) - mean * mean;
  float rs = rsqrtf(var + 1e-5f);
  int c0 = lane * 4;
  ushort4 outv;
  outv.x = f2b((r0 - mean) * rs * ldf(g, gOff + c0 + 0, f) + ldf(bta, btaOff + c0 + 0, f));
  outv.y = f2b((r1 - mean) * rs * ldf(g, gOff + c0 + 1, f) + ldf(bta, btaOff + c0 + 1, f));
  outv.z = f2b((r2 - mean) * rs * ldf(g, gOff + c0 + 2, f) + ldf(bta, btaOff + c0 + 2, f));
  outv.w = f2b((r3 - mean) * rs * ldf(g, gOff + c0 + 3, f) + ldf(bta, btaOff + c0 + 3, f));
  *(ushort4*)xp = outv;
}

// ---------------------------------------------------------------------------
// Head: cls row -> two LNs (shared stats) -> two tiny matvecs.
// ---------------------------------------------------------------------------
__global__ __launch_bounds__(256) void head_kernel(
    const void* dg, const void* dbt, const void* dW, const void* dbias,
    const void* ag, const void* abt, const void* aW, const void* abias,
    void* out)
{
  const int f = g_f32flag;
  const u16* x = g_ws + XOFF;
  int bg = blockIdx.x;
  int tid = threadIdx.x;
  float c = b2f(x[(size_t)bg * S_ * D_ + tid]);
  float s1 = c, s2 = c * c;
#pragma unroll
  for (int off = 32; off > 0; off >>= 1) {
    s1 += __shfl_down(s1, off, 64);
    s2 += __shfl_down(s2, off, 64);
  }
  __shared__ float ws1[4], ws2[4], stats[2];
  __shared__ float lnD[256], lnA[256];
  int wid = tid >> 6, lane = tid & 63;
  if (lane == 0) { ws1[wid] = s1; ws2[wid] = s2; }
  __syncthreads();
  if (tid == 0) {
    float t1 = ws1[0] + ws1[1] + ws1[2] + ws1[3];
    float t2 = ws2[0] + ws2[1] + ws2[2] + ws2[3];
    float mean = t1 * (1.f / 256.f);
    float var = t2 * (1.f / 256.f) - mean * mean;
    stats[0] = mean;
    stats[1] = rsqrtf(var + 1e-5f);
  }
  __syncthreads();
  float n = (c - stats[0]) * stats[1];
  lnD[tid] = n * ldf(dg, tid, f) + ldf(dbt, tid, f);
  lnA[tid] = n * ldf(ag, tid, f) + ldf(abt, tid, f);
  __syncthreads();
  if (tid < NC_) {
    float acc = ldf(dbias, tid, f);
    for (int k = 0; k < D_; k++) acc += lnD[k] * ldf(dW, k * NC_ + tid, f);
    if (f) ((float*)out)[bg * NC_ + tid] = acc;
    else   ((bf16*)out)[bg * NC_ + tid] = __float2bfloat16(acc);
  } else if (tid == 8) {
    float acc = ldf(abias, 0, f);
    for (int k = 0; k < D_; k++) acc += lnA[k] * ldf(aW, k, f);
    if (f) ((float*)out)[B_ * NC_ + bg] = acc;
    else   ((bf16*)out)[B_ * NC_ + bg] = __float2bfloat16(acc);
  }
}

// ---------------------------------------------------------------------------
extern "C" void kernel_launch(void* const* d_in, const int* in_sizes, int n_in,
                              void* d_out, int out_size, void* d_ws, size_t ws_size,
                              hipStream_t stream)
{
  (void)in_sizes; (void)out_size; (void)d_ws; (void)ws_size;
  if (n_in < 34) return;
  const int* token_types  = (const int*)d_in[0];
  const int* decision_ids = (const int*)d_in[1];

  probe_kernel<<<1, 256, 0, stream>>>(d_in[12]);   // pos_embed

  wtrans_kernel<<<(DEPTH_ * D_ * 768 + 255) / 256, 256, 0, stream>>>(
      d_in[14], QKVT_OFF, D_, 768, DEPTH_ * D_ * 768);
  wtrans_kernel<<<(DEPTH_ * D_ * D_ + 255) / 256, 256, 0, stream>>>(
      d_in[16], OUTT_OFF, D_, D_, DEPTH_ * D_ * D_);
  wtrans_kernel<<<(DEPTH_ * D_ * FF_ + 255) / 256, 256, 0, stream>>>(
      d_in[22], FFN1T_OFF, D_, FF_, DEPTH_ * D_ * FF_);
  wtrans_kernel<<<(DEPTH_ * FF_ * D_ + 255) / 256, 256, 0, stream>>>(
      d_in[24], FFN2T_OFF, FF_, D_, DEPTH_ * FF_ * D_);

  embed_kernel<<<MTOT, 256, 0, stream>>>(token_types, decision_ids,
      d_in[2], d_in[3], d_in[4], d_in[5], d_in[6], d_in[7], d_in[8],
      d_in[9], d_in[10], d_in[11], d_in[12], d_in[13]);

  for (int i = 0; i < DEPTH_; i++) {
    gemm_mfma<<<6 * MT128, 256, 0, stream>>>(XOFF,
        QKVT_OFF + i * D_ * 768, d_in[15], (size_t)i * 768, C1OFF, 768, D_, 0, 6);
    attn_kernel<<<B_ * H_, 320, 0, stream>>>();
    gemm_mfma<<<2 * MT128, 256, 0, stream>>>(C2OFF,
        OUTT_OFF + i * D_ * D_, d_in[17], (size_t)i * D_, C1OFF, D_, D_, 0, 2);   // y1 -> c1
    resln_kernel<<<MTOT / 4, 256, 0, stream>>>(C1OFF,
        d_in[18], (size_t)i * D_, d_in[19], (size_t)i * D_);
    gemm_mfma<<<8 * MT128, 256, 0, stream>>>(XOFF,
        FFN1T_OFF + i * D_ * FF_, d_in[23], (size_t)i * FF_, C1OFF, FF_, D_, 1, 8);
    gemm_mfma<<<2 * MT128, 256, 0, stream>>>(C1OFF,
        FFN2T_OFF + i * FF_ * D_, d_in[25], (size_t)i * D_, C2OFF, D_, FF_, 0, 2); // y2 -> c2
    resln_kernel<<<MTOT / 4, 256, 0, stream>>>(C2OFF,
        d_in[20], (size_t)i * D_, d_in[21], (size_t)i * D_);
  }
  head_kernel<<<B_, 256, 0, stream>>>(d_in[26], d_in[27], d_in[28], d_in[29],
      d_in[30], d_in[31], d_in[32], d_in[33], d_out);
}